// Round 1
// baseline (211.160 us; speedup 1.0000x reference)
//
#include <hip/hip_runtime.h>
#include <hip/hip_fp16.h>
#include <math.h>

typedef _Float16 f16;
typedef __attribute__((ext_vector_type(8))) _Float16 f16x8;
typedef __attribute__((ext_vector_type(4))) float f32x4;

#define Bn 4
#define Ln 256
#define Qn 128
#define Hn 1024
#define LBL 33
#define POUT 32896  // 256*257/2

__device__ __forceinline__ float gelu_exact(float x){
    return 0.5f * x * (1.0f + erff(x * 0.70710678118654752f));
}

__device__ __forceinline__ bool mask_at(const void* m, int idx, unsigned u0){
    if (u0 == 0x01010101u) return ((const unsigned char*)m)[idx] != 0;
    if (u0 == 0x3f800000u) return ((const float*)m)[idx] != 0.0f;
    return ((const int*)m)[idx] != 0;
}

// ---------------- generic NN GEMM: C = A(f32,MxK) @ W(f32,KxN) + bias ----------------
// EPI: 1 = gelu -> f32 out ; 2 = plain -> f16 out
template<int EPI>
__global__ __launch_bounds__(256) void gemm_nn(
    const float* __restrict__ A, int lda,
    const float* __restrict__ W, int ldw,
    const float* __restrict__ bias,
    float* __restrict__ Cf, f16* __restrict__ Ch, int ldc, int K)
{
    __shared__ __align__(16) f16 Ah[64][40];
    __shared__ __align__(16) f16 Bh[64][40];
    const int tid = threadIdx.x;
    const int bm = blockIdx.x, bn = blockIdx.y;
    const int w = tid >> 6, lane = tid & 63;
    const int wr = w >> 1, wc = w & 1;
    const int lr = lane & 15, lk = (lane >> 4) * 8;

    f32x4 acc[2][2] = {};

    const int ar = tid >> 2, ag = (tid & 3) * 8;   // A staging: row, col0
    const int wk = tid >> 3, wg = (tid & 7) * 8;   // W staging: k-row, n0
    const float* Aptr = A + (size_t)(bm*64 + ar) * lda + ag;
    const float* Wptr = W + (size_t)wk * ldw + bn*64 + wg;

    for (int k0 = 0; k0 < K; k0 += 32) {
        const float4* ap = (const float4*)(Aptr + k0);
        float4 a0 = ap[0], a1 = ap[1];
        const float4* wp = (const float4*)(Wptr + (size_t)k0 * ldw);
        float4 w0 = wp[0], w1 = wp[1];

        f16x8 av;
        av[0]=(f16)a0.x; av[1]=(f16)a0.y; av[2]=(f16)a0.z; av[3]=(f16)a0.w;
        av[4]=(f16)a1.x; av[5]=(f16)a1.y; av[6]=(f16)a1.z; av[7]=(f16)a1.w;
        *(f16x8*)&Ah[ar][ag] = av;
        // transposed store of W tile
        Bh[wg+0][wk]=(f16)w0.x; Bh[wg+1][wk]=(f16)w0.y;
        Bh[wg+2][wk]=(f16)w0.z; Bh[wg+3][wk]=(f16)w0.w;
        Bh[wg+4][wk]=(f16)w1.x; Bh[wg+5][wk]=(f16)w1.y;
        Bh[wg+6][wk]=(f16)w1.z; Bh[wg+7][wk]=(f16)w1.w;
        __syncthreads();

        f16x8 a[2], b[2];
        #pragma unroll
        for (int mf=0; mf<2; mf++) a[mf] = *(f16x8*)&Ah[wr*32+mf*16+lr][lk];
        #pragma unroll
        for (int nf=0; nf<2; nf++) b[nf] = *(f16x8*)&Bh[wc*32+nf*16+lr][lk];
        #pragma unroll
        for (int mf=0; mf<2; mf++)
            #pragma unroll
            for (int nf=0; nf<2; nf++)
                acc[mf][nf] = __builtin_amdgcn_mfma_f32_16x16x32_f16(a[mf], b[nf], acc[mf][nf], 0, 0, 0);
        __syncthreads();
    }

    const int r0 = (lane >> 4) * 4;
    #pragma unroll
    for (int nf=0; nf<2; nf++){
        const int col = bn*64 + wc*32 + nf*16 + lr;
        const float bv = bias[col];
        #pragma unroll
        for (int mf=0; mf<2; mf++){
            #pragma unroll
            for (int r=0; r<4; r++){
                const int row = bm*64 + wr*32 + mf*16 + r0 + r;
                float v = acc[mf][nf][r] + bv;
                if (EPI == 1) { v = gelu_exact(v); Cf[(size_t)row*ldc + col] = v; }
                else          { Ch[(size_t)row*ldc + col] = (f16)v; }
            }
        }
    }
}

// ---------------- score einsum: score[b,c,q,v] = (qh . ch)/32, masked ----------------
__global__ __launch_bounds__(256) void score_nt(
    const f16* __restrict__ qh, const f16* __restrict__ chh,
    const void* __restrict__ maskp, float* __restrict__ score)
{
    const int bc = blockIdx.z, b = bc >> 1, c = bc & 1;
    const int m0 = blockIdx.x * 64, n0 = blockIdx.y * 64;
    const f16* Aq = qh  + (size_t)b*Qn*2048 + c*1024;
    const f16* Bv = chh + (size_t)b*Ln*2048 + c*1024;

    __shared__ __align__(16) f16 Ah[64][72];
    __shared__ __align__(16) f16 Bh[64][72];
    const int tid = threadIdx.x;
    const int w = tid >> 6, lane = tid & 63;
    const int wr = w >> 1, wc = w & 1;
    const int lr = lane & 15, lk = (lane >> 4) * 8;
    const int rr = tid >> 3, gg = (tid & 7) * 8;

    f32x4 acc[2][2] = {};

    for (int k0 = 0; k0 < 1024; k0 += 64) {
        *(f16x8*)&Ah[rr   ][gg] = *(const f16x8*)(Aq + (size_t)(m0+rr   )*2048 + k0 + gg);
        *(f16x8*)&Ah[rr+32][gg] = *(const f16x8*)(Aq + (size_t)(m0+rr+32)*2048 + k0 + gg);
        *(f16x8*)&Bh[rr   ][gg] = *(const f16x8*)(Bv + (size_t)(n0+rr   )*2048 + k0 + gg);
        *(f16x8*)&Bh[rr+32][gg] = *(const f16x8*)(Bv + (size_t)(n0+rr+32)*2048 + k0 + gg);
        __syncthreads();
        #pragma unroll
        for (int ks=0; ks<64; ks+=32){
            f16x8 a[2], b[2];
            #pragma unroll
            for (int mf=0; mf<2; mf++) a[mf] = *(f16x8*)&Ah[wr*32+mf*16+lr][ks+lk];
            #pragma unroll
            for (int nf=0; nf<2; nf++) b[nf] = *(f16x8*)&Bh[wc*32+nf*16+lr][ks+lk];
            #pragma unroll
            for (int mf=0; mf<2; mf++)
                #pragma unroll
                for (int nf=0; nf<2; nf++)
                    acc[mf][nf] = __builtin_amdgcn_mfma_f32_16x16x32_f16(a[mf], b[nf], acc[mf][nf], 0, 0, 0);
        }
        __syncthreads();
    }

    const unsigned u0 = *(const unsigned*)maskp;
    const int r0 = (lane >> 4) * 4;
    #pragma unroll
    for (int nf=0; nf<2; nf++){
        const int v = n0 + wc*32 + nf*16 + lr;
        const bool mv = mask_at(maskp, b*Ln + v, u0);
        #pragma unroll
        for (int mf=0; mf<2; mf++){
            #pragma unroll
            for (int r=0; r<4; r++){
                const int q = m0 + wr*32 + mf*16 + r0 + r;
                float val = mv ? (acc[mf][nf][r] * 0.03125f) : -100000000.0f;
                score[((size_t)(b*2+c)*Qn + q)*Ln + v] = val;
            }
        }
    }
}

// ---------------- cls head: logits = X1@w2 + b2 + qlog ; softmax -> out0 ----------------
__global__ __launch_bounds__(256) void cls2_softmax(
    const float* __restrict__ X1, const float* __restrict__ w2,
    const float* __restrict__ b2, const float* __restrict__ qlog,
    float* __restrict__ out0)
{
    const int row = blockIdx.x, t = threadIdx.x;
    __shared__ float xr[512];
    __shared__ float lg[LBL];
    __shared__ float mx_s, si_s;
    xr[t]       = X1[(size_t)row*512 + t];
    xr[t + 256] = X1[(size_t)row*512 + t + 256];
    __syncthreads();

    const int c = t >> 2, s = t & 3;   // c in 0..63, 4 threads per column
    float acc = 0.0f;
    if (c < LBL){
        for (int k = s*128; k < (s+1)*128; k++) acc += xr[k] * w2[(size_t)k*LBL + c];
    }
    acc += __shfl_down(acc, 1);
    acc += __shfl_down(acc, 2);
    if (s == 0 && c < LBL) lg[c] = acc + b2[c] + qlog[(size_t)row*LBL + c];
    __syncthreads();
    if (t == 0){
        float mx = -1e30f;
        for (int k=0;k<LBL;k++) mx = fmaxf(mx, lg[k]);
        float sm = 0.0f;
        for (int k=0;k<LBL;k++) sm += __expf(lg[k]-mx);
        mx_s = mx; si_s = 1.0f / sm;
    }
    __syncthreads();
    if (t < LBL) out0[(size_t)row*LBL + t] = __expf(lg[t]-mx_s) * si_s;
}

// ---------------- loc head: loc_out = X2@w2 + b2 -> centers, F = fac@fac^T ----------------
__global__ __launch_bounds__(256) void loc2_geo(
    const float* __restrict__ X2, const float* __restrict__ w2,
    const float* __restrict__ b2, const float* __restrict__ qlocs,
    float* __restrict__ geo)
{
    const int row = blockIdx.x, t = threadIdx.x;
    __shared__ float xr[512];
    __shared__ float vv[8];
    xr[t]       = X2[(size_t)row*512 + t];
    xr[t + 256] = X2[(size_t)row*512 + t + 256];
    __syncthreads();

    const int c = t >> 5, s = t & 31;  // c in 0..7, 32 threads per column
    float acc = 0.0f;
    if (c < 6){
        for (int k = s*16; k < (s+1)*16; k++) acc += xr[k] * w2[(size_t)k*6 + c];
    }
    #pragma unroll
    for (int off=1; off<32; off<<=1) acc += __shfl_down(acc, off);
    if (s == 0 && c < 6) vv[c] = acc + b2[c];
    __syncthreads();
    if (t == 0){
        const float o0=vv[0], o1=vv[1], f0=vv[2], f1=vv[3], f2=vv[4], f3=vv[5];
        geo[(size_t)row*5+0] = qlocs[(size_t)row*2+0] + o0;
        geo[(size_t)row*5+1] = qlocs[(size_t)row*2+1] + o1;
        geo[(size_t)row*5+2] = f0*f0 + f1*f1;
        geo[(size_t)row*5+3] = f0*f2 + f1*f3;
        geo[(size_t)row*5+4] = f2*f2 + f3*f3;
    }
}

// ---------------- pair kernel: locs_pros ----------------
__global__ __launch_bounds__(256) void pair_kernel(
    const float* __restrict__ score, const float* __restrict__ geo,
    float* __restrict__ out1)
{
    const int bq = blockIdx.x;          // b*128 + q
    const int b = bq >> 7, t = threadIdx.x;
    __shared__ float s0[256], s1[256], sfx[256], red[256];

    const float* sc0 = score + ((size_t)(b*2+0)*Qn + (bq & 127))*Ln;
    const float* sc1 = sc0 + (size_t)Qn*Ln;
    s0[t] = sc0[t]; s1[t] = sc1[t]; sfx[t] = s1[t];
    __syncthreads();

    // suffix max of s1
    for (int off=1; off<256; off<<=1){
        float v = sfx[t];
        if (t + off < 256) v = fmaxf(v, sfx[t+off]);
        __syncthreads();
        sfx[t] = v;
        __syncthreads();
    }
    // m = max_i (s0[i] + max_{j>=i} s1[j])
    red[t] = s0[t] + sfx[t];
    __syncthreads();
    for (int off=128; off>0; off>>=1){
        if (t < off) red[t] = fmaxf(red[t], red[t+off]);
        __syncthreads();
    }
    const float m = red[0];
    __syncthreads();

    const float c0  = geo[(size_t)bq*5+0], c1  = geo[(size_t)bq*5+1];
    const float F00 = geo[(size_t)bq*5+2], F01 = geo[(size_t)bq*5+3], F11 = geo[(size_t)bq*5+4];

    // pass 1: sum of e
    float lsum = 0.0f;
    for (int it = 0; it < 129; it++){
        const int p = it*256 + t;
        if (p < POUT){
            const float sq = sqrtf((float)(263169 - 8*p));
            const int i = (int)((513.0f - sq) * 0.5f);
            const int j = i + (p - ((i*(513 - i)) >> 1));
            const float d0 = (float)i - c0, d1 = (float)j - c1;
            const float quad = F00*d0*d0 + 2.0f*F01*d0*d1 + F11*d1*d1;
            lsum += __expf(s0[i] + s1[j] - m - quad);
        }
    }
    __syncthreads();
    red[t] = lsum;
    __syncthreads();
    for (int off=128; off>0; off>>=1){
        if (t < off) red[t] += red[t+off];
        __syncthreads();
    }
    const float inv = 1.0f / (red[0] + 1e-12f);

    float* op = out1 + (size_t)bq * POUT;
    for (int it = 0; it < 129; it++){
        const int p = it*256 + t;
        if (p < POUT){
            const float sq = sqrtf((float)(263169 - 8*p));
            const int i = (int)((513.0f - sq) * 0.5f);
            const int j = i + (p - ((i*(513 - i)) >> 1));
            const float d0 = (float)i - c0, d1 = (float)j - c1;
            const float quad = F00*d0*d0 + 2.0f*F01*d0*d1 + F11*d1*d1;
            op[p] = __expf(s0[i] + s1[j] - m - quad) * inv;
        }
    }
}

extern "C" void kernel_launch(void* const* d_in, const int* in_sizes, int n_in,
                              void* d_out, int out_size, void* d_ws, size_t ws_size,
                              hipStream_t stream)
{
    const float* hiddens = (const float*)d_in[0];
    const void*  masks   = d_in[1];
    const float* queries = (const float*)d_in[2];
    const float* qlocs   = (const float*)d_in[3];
    const float* qlogits = (const float*)d_in[4];
    const float* cls_w1  = (const float*)d_in[5];
    const float* cls_b1  = (const float*)d_in[6];
    const float* cls_w2  = (const float*)d_in[7];
    const float* cls_b2  = (const float*)d_in[8];
    const float* tq_w    = (const float*)d_in[9];
    const float* tq_b    = (const float*)d_in[10];
    const float* tc_w    = (const float*)d_in[11];
    const float* tc_b    = (const float*)d_in[12];
    const float* loc_w1  = (const float*)d_in[13];
    const float* loc_b1  = (const float*)d_in[14];
    const float* loc_w2  = (const float*)d_in[15];
    const float* loc_b2  = (const float*)d_in[16];

    char* ws = (char*)d_ws;
    float* X1    = (float*)(ws);                       // 1 MB  (512x512 f32)
    float* X2    = (float*)(ws + (1u<<20));            // 1 MB
    f16*   qh    = (f16*)  (ws + (2u<<20));            // 2 MB  (512x2048 f16)
    f16*   chh   = (f16*)  (ws + (4u<<20));            // 4 MB  (1024x2048 f16)
    float* score = (float*)(ws + (8u<<20));            // 1 MB  (B,2,Q,L f32)
    float* geo   = (float*)(ws + (9u<<20));            // 10 KB (B*Q x 5)

    float* out0 = (float*)d_out;
    float* out1 = out0 + (size_t)Bn*Qn*LBL;

    // cls1 / loc1: gelu(queries @ w1 + b1) -> f32
    gemm_nn<1><<<dim3(8, 8),  256, 0, stream>>>(queries, Hn, cls_w1, 512, cls_b1, X1, (f16*)nullptr, 512, Hn);
    gemm_nn<1><<<dim3(8, 8),  256, 0, stream>>>(queries, Hn, loc_w1, 512, loc_b1, X2, (f16*)nullptr, 512, Hn);
    // tq / tc -> f16
    gemm_nn<2><<<dim3(8, 32), 256, 0, stream>>>(queries, Hn, tq_w, 2048, tq_b, (float*)nullptr, qh, 2048, Hn);
    gemm_nn<2><<<dim3(16,32), 256, 0, stream>>>(hiddens, Hn, tc_w, 2048, tc_b, (float*)nullptr, chh, 2048, Hn);
    // score einsum + mask
    score_nt<<<dim3(2, 4, 8), 256, 0, stream>>>(qh, chh, masks, score);
    // heads
    cls2_softmax<<<dim3(Bn*Qn), 256, 0, stream>>>(X1, cls_w2, cls_b2, qlogits, out0);
    loc2_geo<<<dim3(Bn*Qn), 256, 0, stream>>>(X2, loc_w2, loc_b2, qlocs, geo);
    // big pair softmax
    pair_kernel<<<dim3(Bn*Qn), 256, 0, stream>>>(score, geo, out1);
}

// Round 2
// 133.998 us; speedup vs baseline: 1.5758x; 1.5758x over previous
//
#include <hip/hip_runtime.h>
#include <math.h>

typedef _Float16 f16;
typedef __attribute__((ext_vector_type(4))) _Float16 f16x4;
typedef __attribute__((ext_vector_type(8))) _Float16 f16x8;
typedef __attribute__((ext_vector_type(4))) float f32x4;

#define Bn 4
#define Ln 256
#define Qn 128
#define Hn 1024
#define LBL 33
#define POUT 32896   // 256*257/2
#define SLICE 4112   // POUT/8

__device__ __forceinline__ float gelu_exact(float x){
    return 0.5f * x * (1.0f + erff(x * 0.70710678118654752f));
}

__device__ __forceinline__ bool mask_at(const void* m, int idx, unsigned u0){
    if (u0 == 0x01010101u) return ((const unsigned char*)m)[idx] != 0;
    if (u0 == 0x3f800000u) return ((const float*)m)[idx] != 0.0f;
    return ((const int*)m)[idx] != 0;
}

// ---------------- convert activations f32 -> f16 ----------------
__global__ __launch_bounds__(256) void cvt_inputs(
    const float* __restrict__ q, const float* __restrict__ h,
    f16* __restrict__ qf, f16* __restrict__ hf)
{
    const int gid = blockIdx.x * 256 + threadIdx.x;   // 0..393215
    if (gid < 131072) {
        const float4 v = ((const float4*)q)[gid];
        f16x4 o; o[0]=(f16)v.x; o[1]=(f16)v.y; o[2]=(f16)v.z; o[3]=(f16)v.w;
        *(f16x4*)&qf[(size_t)gid*4] = o;
    } else {
        const int g = gid - 131072;
        const float4 v = ((const float4*)h)[g];
        f16x4 o; o[0]=(f16)v.x; o[1]=(f16)v.y; o[2]=(f16)v.z; o[3]=(f16)v.w;
        *(f16x4*)&hf[(size_t)g*4] = o;
    }
}

// ---------------- convert+transpose weights: [1024][N] f32 -> [N][1024] f16 ----------------
__global__ __launch_bounds__(256) void cvt_transpose(
    const float* __restrict__ cls_w1, const float* __restrict__ loc_w1,
    const float* __restrict__ tq_w,  const float* __restrict__ tc_w,
    f16* __restrict__ Wq_t, f16* __restrict__ Wc_t)
{
    const int z = blockIdx.z;
    const float* src; int N; f16* dst;
    if      (z == 0) { src = cls_w1; N = 512;  dst = Wq_t; }
    else if (z == 1) { src = loc_w1; N = 512;  dst = Wq_t + (size_t)512*1024; }
    else if (z == 2) { src = tq_w;   N = 2048; dst = Wq_t + (size_t)1024*1024; }
    else             { src = tc_w;   N = 2048; dst = Wc_t; }
    const int n0 = blockIdx.x * 32;
    if (n0 >= N) return;
    const int k0 = blockIdx.y * 32;

    __shared__ f16 T[32][36];
    const int t = threadIdx.x;
    const int r = t >> 3, c4 = (t & 7) * 4;
    const float4 v = *(const float4*)&src[(size_t)(k0 + r) * N + n0 + c4];
    T[c4+0][r] = (f16)v.x; T[c4+1][r] = (f16)v.y;
    T[c4+2][r] = (f16)v.z; T[c4+3][r] = (f16)v.w;
    __syncthreads();
    f16x4 o;
    o[0] = T[t>>3][(t&7)*4+0]; o[1] = T[t>>3][(t&7)*4+1];
    o[2] = T[t>>3][(t&7)*4+2]; o[3] = T[t>>3][(t&7)*4+3];
    *(f16x4*)&dst[(size_t)(n0 + (t>>3)) * 1024 + k0 + (t&7)*4] = o;
}

// ---------------- GEMM: C = A(f16 MxK) @ Bt(f16 NxK)^T, K=1024, tile 64x64 ----------------
// EPI 0: q-side fused: col<512 gelu->X1 ; col<1024 gelu->X2 ; else bias->f16 qh
// EPI 1: c-side: bias -> f16 chh
template<int EPI>
__global__ __launch_bounds__(256) void gemm_bt(
    const f16* __restrict__ A, const f16* __restrict__ Bt,
    const float* __restrict__ b0p, const float* __restrict__ b1p, const float* __restrict__ b2p,
    float* __restrict__ X1, float* __restrict__ X2, f16* __restrict__ Oh)
{
    __shared__ __align__(16) f16 Ah[64][72];
    __shared__ __align__(16) f16 Bh[64][72];
    const int tid = threadIdx.x;
    const int bm = blockIdx.x, bn = blockIdx.y;
    const int w = tid >> 6, lane = tid & 63;
    const int wr = w >> 1, wc = w & 1;
    const int lr = lane & 15, lk = (lane >> 4) * 8;

    f32x4 acc[2][2] = {};

    const int srow = tid >> 2, scol = (tid & 3) * 16;
    const f16* Ap = A  + (size_t)(bm*64 + srow) * 1024 + scol;
    const f16* Bp = Bt + (size_t)(bn*64 + srow) * 1024 + scol;

    for (int k0 = 0; k0 < 1024; k0 += 64) {
        *(f16x8*)&Ah[srow][scol]     = *(const f16x8*)(Ap + k0);
        *(f16x8*)&Ah[srow][scol + 8] = *(const f16x8*)(Ap + k0 + 8);
        *(f16x8*)&Bh[srow][scol]     = *(const f16x8*)(Bp + k0);
        *(f16x8*)&Bh[srow][scol + 8] = *(const f16x8*)(Bp + k0 + 8);
        __syncthreads();
        #pragma unroll
        for (int ks = 0; ks < 64; ks += 32) {
            f16x8 a[2], b[2];
            #pragma unroll
            for (int mf = 0; mf < 2; mf++) a[mf] = *(f16x8*)&Ah[wr*32 + mf*16 + lr][ks + lk];
            #pragma unroll
            for (int nf = 0; nf < 2; nf++) b[nf] = *(f16x8*)&Bh[wc*32 + nf*16 + lr][ks + lk];
            #pragma unroll
            for (int mf = 0; mf < 2; mf++)
                #pragma unroll
                for (int nf = 0; nf < 2; nf++)
                    acc[mf][nf] = __builtin_amdgcn_mfma_f32_16x16x32_f16(a[mf], b[nf], acc[mf][nf], 0, 0, 0);
        }
        __syncthreads();
    }

    const int r0 = (lane >> 4) * 4;
    #pragma unroll
    for (int nf = 0; nf < 2; nf++) {
        const int col = bn*64 + wc*32 + nf*16 + lr;
        #pragma unroll
        for (int mf = 0; mf < 2; mf++) {
            #pragma unroll
            for (int r = 0; r < 4; r++) {
                const int row = bm*64 + wr*32 + mf*16 + r0 + r;
                const float v = acc[mf][nf][r];
                if (EPI == 0) {
                    if (col < 512)       X1[(size_t)row*512 + col]        = gelu_exact(v + b0p[col]);
                    else if (col < 1024) X2[(size_t)row*512 + col - 512]  = gelu_exact(v + b1p[col-512]);
                    else                 Oh[(size_t)row*2048 + col - 1024] = (f16)(v + b2p[col-1024]);
                } else {
                    Oh[(size_t)row*2048 + col] = (f16)(v + b0p[col]);
                }
            }
        }
    }
}

// ---------------- score einsum: score[b,c,q,v] = (qh . ch)/32, masked ----------------
__global__ __launch_bounds__(256) void score_nt(
    const f16* __restrict__ qh, const f16* __restrict__ chh,
    const void* __restrict__ maskp, float* __restrict__ score)
{
    const int bc = blockIdx.z, b = bc >> 1, c = bc & 1;
    const int m0 = blockIdx.x * 64, n0 = blockIdx.y * 64;
    const f16* Aq = qh  + (size_t)b*Qn*2048 + c*1024;
    const f16* Bv = chh + (size_t)b*Ln*2048 + c*1024;

    __shared__ __align__(16) f16 Ah[64][72];
    __shared__ __align__(16) f16 Bh[64][72];
    const int tid = threadIdx.x;
    const int w = tid >> 6, lane = tid & 63;
    const int wr = w >> 1, wc = w & 1;
    const int lr = lane & 15, lk = (lane >> 4) * 8;
    const int rr = tid >> 3, gg = (tid & 7) * 8;

    f32x4 acc[2][2] = {};

    for (int k0 = 0; k0 < 1024; k0 += 64) {
        *(f16x8*)&Ah[rr   ][gg] = *(const f16x8*)(Aq + (size_t)(m0+rr   )*2048 + k0 + gg);
        *(f16x8*)&Ah[rr+32][gg] = *(const f16x8*)(Aq + (size_t)(m0+rr+32)*2048 + k0 + gg);
        *(f16x8*)&Bh[rr   ][gg] = *(const f16x8*)(Bv + (size_t)(n0+rr   )*2048 + k0 + gg);
        *(f16x8*)&Bh[rr+32][gg] = *(const f16x8*)(Bv + (size_t)(n0+rr+32)*2048 + k0 + gg);
        __syncthreads();
        #pragma unroll
        for (int ks=0; ks<64; ks+=32){
            f16x8 a[2], b[2];
            #pragma unroll
            for (int mf=0; mf<2; mf++) a[mf] = *(f16x8*)&Ah[wr*32+mf*16+lr][ks+lk];
            #pragma unroll
            for (int nf=0; nf<2; nf++) b[nf] = *(f16x8*)&Bh[wc*32+nf*16+lr][ks+lk];
            #pragma unroll
            for (int mf=0; mf<2; mf++)
                #pragma unroll
                for (int nf=0; nf<2; nf++)
                    acc[mf][nf] = __builtin_amdgcn_mfma_f32_16x16x32_f16(a[mf], b[nf], acc[mf][nf], 0, 0, 0);
        }
        __syncthreads();
    }

    const unsigned u0 = *(const unsigned*)maskp;
    const int r0 = (lane >> 4) * 4;
    #pragma unroll
    for (int nf=0; nf<2; nf++){
        const int v = n0 + wc*32 + nf*16 + lr;
        const bool mv = mask_at(maskp, b*Ln + v, u0);
        #pragma unroll
        for (int mf=0; mf<2; mf++){
            #pragma unroll
            for (int r=0; r<4; r++){
                const int q = m0 + wr*32 + mf*16 + r0 + r;
                float val = mv ? (acc[mf][nf][r] * 0.03125f) : -100000000.0f;
                score[((size_t)(b*2+c)*Qn + q)*Ln + v] = val;
            }
        }
    }
}

// ---------------- fused heads: blocks 0..511 cls softmax, 512..1023 loc geo ----------------
__global__ __launch_bounds__(256) void heads(
    const float* __restrict__ X1, const float* __restrict__ cls_w2,
    const float* __restrict__ cls_b2, const float* __restrict__ qlog, float* __restrict__ out0,
    const float* __restrict__ X2, const float* __restrict__ loc_w2,
    const float* __restrict__ loc_b2, const float* __restrict__ qlocs, float* __restrict__ geo)
{
    const int blk = blockIdx.x, t = threadIdx.x;
    __shared__ float xr[512];
    __shared__ float lg[64];
    __shared__ float mx_s, si_s;
    if (blk < 512) {
        const int row = blk;
        xr[t]       = X1[(size_t)row*512 + t];
        xr[t + 256] = X1[(size_t)row*512 + t + 256];
        __syncthreads();
        const int c = t >> 2, s = t & 3;
        float acc = 0.0f;
        if (c < LBL){
            for (int k = s*128; k < (s+1)*128; k++) acc += xr[k] * cls_w2[(size_t)k*LBL + c];
        }
        acc += __shfl_down(acc, 1);
        acc += __shfl_down(acc, 2);
        if (s == 0 && c < LBL) lg[c] = acc + cls_b2[c] + qlog[(size_t)row*LBL + c];
        __syncthreads();
        if (t == 0){
            float mx = -1e30f;
            for (int k=0;k<LBL;k++) mx = fmaxf(mx, lg[k]);
            float sm = 0.0f;
            for (int k=0;k<LBL;k++) sm += __expf(lg[k]-mx);
            mx_s = mx; si_s = 1.0f / sm;
        }
        __syncthreads();
        if (t < LBL) out0[(size_t)row*LBL + t] = __expf(lg[t]-mx_s) * si_s;
    } else {
        const int row = blk - 512;
        xr[t]       = X2[(size_t)row*512 + t];
        xr[t + 256] = X2[(size_t)row*512 + t + 256];
        __syncthreads();
        const int c = t >> 5, s = t & 31;
        float acc = 0.0f;
        if (c < 6){
            for (int k = s*16; k < (s+1)*16; k++) acc += xr[k] * loc_w2[(size_t)k*6 + c];
        }
        #pragma unroll
        for (int off=1; off<32; off<<=1) acc += __shfl_down(acc, off);
        if (s == 0 && c < 6) lg[c] = acc + loc_b2[c];
        __syncthreads();
        if (t == 0){
            const float o0=lg[0], o1=lg[1], f0=lg[2], f1=lg[3], f2=lg[4], f3=lg[5];
            geo[(size_t)row*5+0] = qlocs[(size_t)row*2+0] + o0;
            geo[(size_t)row*5+1] = qlocs[(size_t)row*2+1] + o1;
            geo[(size_t)row*5+2] = f0*f0 + f1*f1;
            geo[(size_t)row*5+3] = f0*f2 + f1*f3;
            geo[(size_t)row*5+4] = f2*f2 + f3*f3;
        }
    }
}

// ---------------- pair reduce: per (bq, slice) partial sums; slice 0 stores m ----------------
__global__ __launch_bounds__(256) void pair_reduce(
    const float* __restrict__ score, const float* __restrict__ geo,
    float* __restrict__ sums, float* __restrict__ mvals)
{
    const int bq = blockIdx.x, sl = blockIdx.y;
    const int b = bq >> 7, t = threadIdx.x;
    __shared__ float s0[256], s1[256], sfx[256], red[256];

    const float* sc0 = score + ((size_t)(b*2+0)*Qn + (bq & 127))*Ln;
    const float* sc1 = sc0 + (size_t)Qn*Ln;
    s0[t] = sc0[t]; s1[t] = sc1[t]; sfx[t] = s1[t];
    __syncthreads();

    for (int off=1; off<256; off<<=1){
        float v = sfx[t];
        if (t + off < 256) v = fmaxf(v, sfx[t+off]);
        __syncthreads();
        sfx[t] = v;
        __syncthreads();
    }
    red[t] = s0[t] + sfx[t];
    __syncthreads();
    for (int off=128; off>0; off>>=1){
        if (t < off) red[t] = fmaxf(red[t], red[t+off]);
        __syncthreads();
    }
    const float m = red[0];
    __syncthreads();

    const float c0  = geo[(size_t)bq*5+0], c1  = geo[(size_t)bq*5+1];
    const float F00 = geo[(size_t)bq*5+2], F01 = geo[(size_t)bq*5+3], F11 = geo[(size_t)bq*5+4];

    const int base = sl * SLICE, end = base + SLICE;
    float lsum = 0.0f;
    for (int p = base + t; p < end; p += 256){
        const float sq = sqrtf((float)(263169 - 8*p));
        const int i = (int)((513.0f - sq) * 0.5f);
        const int j = i + (p - ((i*(513 - i)) >> 1));
        const float d0 = (float)i - c0, d1 = (float)j - c1;
        const float quad = fmaf(fmaf(F11, d1, 2.0f*F01*d0), d1, F00*d0*d0);
        lsum += __expf(s0[i] + s1[j] - m - quad);
    }
    __syncthreads();
    red[t] = lsum;
    __syncthreads();
    for (int off=128; off>0; off>>=1){
        if (t < off) red[t] += red[t+off];
        __syncthreads();
    }
    if (t == 0){
        sums[bq*8 + sl] = red[0];
        if (sl == 0) mvals[bq] = m;
    }
}

// ---------------- pair write: normalize + store slice ----------------
__global__ __launch_bounds__(256) void pair_write(
    const float* __restrict__ score, const float* __restrict__ geo,
    const float* __restrict__ sums, const float* __restrict__ mvals,
    float* __restrict__ out1)
{
    const int bq = blockIdx.x, sl = blockIdx.y;
    const int b = bq >> 7, t = threadIdx.x;
    __shared__ float s0[256], s1[256];
    __shared__ float invs;

    const float* sc0 = score + ((size_t)(b*2+0)*Qn + (bq & 127))*Ln;
    const float* sc1 = sc0 + (size_t)Qn*Ln;
    s0[t] = sc0[t]; s1[t] = sc1[t];
    if (t == 0){
        float tot = 0.0f;
        #pragma unroll
        for (int k=0;k<8;k++) tot += sums[bq*8 + k];
        invs = 1.0f / (tot + 1e-12f);
    }
    __syncthreads();

    const float m = mvals[bq];
    const float inv = invs;
    const float c0  = geo[(size_t)bq*5+0], c1  = geo[(size_t)bq*5+1];
    const float F00 = geo[(size_t)bq*5+2], F01 = geo[(size_t)bq*5+3], F11 = geo[(size_t)bq*5+4];

    float* op = out1 + (size_t)bq * POUT;
    const int base = sl * SLICE, end = base + SLICE;
    for (int p = base + t; p < end; p += 256){
        const float sq = sqrtf((float)(263169 - 8*p));
        const int i = (int)((513.0f - sq) * 0.5f);
        const int j = i + (p - ((i*(513 - i)) >> 1));
        const float d0 = (float)i - c0, d1 = (float)j - c1;
        const float quad = fmaf(fmaf(F11, d1, 2.0f*F01*d0), d1, F00*d0*d0);
        op[p] = __expf(s0[i] + s1[j] - m - quad) * inv;
    }
}

extern "C" void kernel_launch(void* const* d_in, const int* in_sizes, int n_in,
                              void* d_out, int out_size, void* d_ws, size_t ws_size,
                              hipStream_t stream)
{
    const float* hiddens = (const float*)d_in[0];
    const void*  masks   = d_in[1];
    const float* queries = (const float*)d_in[2];
    const float* qlocs   = (const float*)d_in[3];
    const float* qlogits = (const float*)d_in[4];
    const float* cls_w1  = (const float*)d_in[5];
    const float* cls_b1  = (const float*)d_in[6];
    const float* cls_w2  = (const float*)d_in[7];
    const float* cls_b2  = (const float*)d_in[8];
    const float* tq_w    = (const float*)d_in[9];
    const float* tq_b    = (const float*)d_in[10];
    const float* tc_w    = (const float*)d_in[11];
    const float* tc_b    = (const float*)d_in[12];
    const float* loc_w1  = (const float*)d_in[13];
    const float* loc_b1  = (const float*)d_in[14];
    const float* loc_w2  = (const float*)d_in[15];
    const float* loc_b2  = (const float*)d_in[16];

    // ws scratch (stays under the ~9 MB proven footprint)
    char* ws = (char*)d_ws;
    f16*   qf16  = (f16*)  (ws);                     // 1 MB  (512x1024)
    f16*   hf16  = (f16*)  (ws + (1u<<20));          // 2 MB  (1024x1024)
    float* X1    = (float*)(ws + (3u<<20));          // 1 MB  (512x512)
    float* X2    = (float*)(ws + (4u<<20));          // 1 MB
    f16*   qh    = (f16*)  (ws + (5u<<20));          // 2 MB  (512x2048)
    float* score = (float*)(ws + (7u<<20));          // 1 MB  (B,2,Q,L)
    float* geo   = (float*)(ws + (8u<<20));          // 10 KB
    float* sums  = (float*)(ws + (8u<<20) + 0x4000); // 16 KB
    float* mvals = (float*)(ws + (8u<<20) + 0x8000); // 2 KB

    float* out0 = (float*)d_out;
    float* out1 = out0 + (size_t)Bn*Qn*LBL;

    // big transient scratch inside out1 (fully overwritten by pair_write at the end)
    f16* Wq_t = (f16*)out1;                                   // 3072x1024 f16 = 6 MB
    f16* Wc_t = (f16*)((char*)out1 + 6291456);                // 2048x1024 f16 = 4 MB
    f16* chh  = (f16*)((char*)out1 + 6291456 + 4194304);      // 1024x2048 f16 = 4 MB

    cvt_inputs   <<<dim3(1536), 256, 0, stream>>>(queries, hiddens, qf16, hf16);
    cvt_transpose<<<dim3(64, 32, 4), 256, 0, stream>>>(cls_w1, loc_w1, tq_w, tc_w, Wq_t, Wc_t);

    // q-side fused GEMM: M=512, N=3072 (cls1 | loc1 | tq)
    gemm_bt<0><<<dim3(8, 48), 256, 0, stream>>>(qf16, Wq_t, cls_b1, loc_b1, tq_b, X1, X2, qh);
    // c-side GEMM: M=1024, N=2048 (tc)
    gemm_bt<1><<<dim3(16, 32), 256, 0, stream>>>(hf16, Wc_t, tc_b, nullptr, nullptr, nullptr, nullptr, chh);

    score_nt<<<dim3(2, 4, 8), 256, 0, stream>>>(qh, chh, masks, score);
    heads   <<<dim3(1024), 256, 0, stream>>>(X1, cls_w2, cls_b2, qlogits, out0,
                                             X2, loc_w2, loc_b2, qlocs, geo);
    pair_reduce<<<dim3(Bn*Qn, 8), 256, 0, stream>>>(score, geo, sums, mvals);
    pair_write <<<dim3(Bn*Qn, 8), 256, 0, stream>>>(score, geo, sums, mvals, out1);
}

// Round 3
// 122.983 us; speedup vs baseline: 1.7170x; 1.0896x over previous
//
#include <hip/hip_runtime.h>
#include <math.h>

typedef _Float16 f16;
typedef __attribute__((ext_vector_type(4))) _Float16 f16x4;
typedef __attribute__((ext_vector_type(8))) _Float16 f16x8;
typedef __attribute__((ext_vector_type(4))) float f32x4;

#define Bn 4
#define Ln 256
#define Qn 128
#define Hn 1024
#define LBL 33
#define POUT 32896   // 256*257/2
#define SLICE 4112   // POUT/8

__device__ __forceinline__ float gelu_exact(float x){
    return 0.5f * x * (1.0f + erff(x * 0.70710678118654752f));
}

__device__ __forceinline__ bool mask_at(const void* m, int idx, unsigned u0){
    if (u0 == 0x01010101u) return ((const unsigned char*)m)[idx] != 0;
    if (u0 == 0x3f800000u) return ((const float*)m)[idx] != 0.0f;
    return ((const int*)m)[idx] != 0;
}

__device__ __forceinline__ void gload16(const void* g, void* l){
    __builtin_amdgcn_global_load_lds(
        (const __attribute__((address_space(1))) unsigned int*)g,
        (__attribute__((address_space(3))) unsigned int*)l, 16, 0, 0);
}

// ---------------- prep: input f32->f16 cvt + weight cvt/transpose ----------------
// blocks [0,512): queries cvt ; [512,1536): hiddens cvt ; [1536,6656): weight transpose tiles
__global__ __launch_bounds__(256) void prep(
    const float* __restrict__ q, const float* __restrict__ h,
    const float* __restrict__ cls_w1, const float* __restrict__ loc_w1,
    const float* __restrict__ tq_w,  const float* __restrict__ tc_w,
    f16* __restrict__ qf, f16* __restrict__ hf,
    f16* __restrict__ Wq_t, f16* __restrict__ Wc_t)
{
    const int bx = blockIdx.x, t = threadIdx.x;
    if (bx < 1536) {
        if (bx < 512) {
            const int gid = bx*256 + t;
            const float4 v = ((const float4*)q)[gid];
            f16x4 o; o[0]=(f16)v.x; o[1]=(f16)v.y; o[2]=(f16)v.z; o[3]=(f16)v.w;
            *(f16x4*)&qf[(size_t)gid*4] = o;
        } else {
            const int gid = (bx-512)*256 + t;
            const float4 v = ((const float4*)h)[gid];
            f16x4 o; o[0]=(f16)v.x; o[1]=(f16)v.y; o[2]=(f16)v.z; o[3]=(f16)v.w;
            *(f16x4*)&hf[(size_t)gid*4] = o;
        }
        return;
    }
    const int tile = bx - 1536;     // 0..5119
    const float* src; f16* dst; int id, lg;
    if      (tile < 512)  { id = tile;        src = cls_w1; dst = Wq_t;                        lg = 4; }
    else if (tile < 1024) { id = tile - 512;  src = loc_w1; dst = Wq_t + (size_t)512*1024;     lg = 4; }
    else if (tile < 3072) { id = tile - 1024; src = tq_w;   dst = Wq_t + (size_t)1024*1024;    lg = 6; }
    else                  { id = tile - 3072; src = tc_w;   dst = Wc_t;                        lg = 6; }
    const int N  = 32 << lg;
    const int n0 = (id & ((1<<lg)-1)) * 32;
    const int k0 = (id >> lg) * 32;

    __shared__ f16 T[32][36];
    const int r = t >> 3, c4 = (t & 7) * 4;
    const float4 v = *(const float4*)&src[(size_t)(k0 + r) * N + n0 + c4];
    T[c4+0][r] = (f16)v.x; T[c4+1][r] = (f16)v.y;
    T[c4+2][r] = (f16)v.z; T[c4+3][r] = (f16)v.w;
    __syncthreads();
    f16x4 o;
    o[0] = T[t>>3][(t&7)*4+0]; o[1] = T[t>>3][(t&7)*4+1];
    o[2] = T[t>>3][(t&7)*4+2]; o[3] = T[t>>3][(t&7)*4+3];
    *(f16x4*)&dst[(size_t)(n0 + (t>>3)) * 1024 + k0 + (t&7)*4] = o;
}

// ---------------- fused 128x128-tile GEMM (m97 structure), K=1024 ----------------
// blocks [0,96): q-side M=512,N=3072 (cls1|loc1|tq epilogues)
// blocks [96,224): c-side M=1024,N=2048 (tc -> f16 chh)
__global__ __launch_bounds__(256) void gemm128(
    const f16* __restrict__ Aq, const f16* __restrict__ Ac,
    const f16* __restrict__ Wq, const f16* __restrict__ Wc,
    const float* __restrict__ cb1, const float* __restrict__ lb1,
    const float* __restrict__ tqb, const float* __restrict__ tcb,
    float* __restrict__ X1, float* __restrict__ X2,
    f16* __restrict__ qh, f16* __restrict__ chh)
{
    __shared__ __align__(16) f16 Ah[128*64];
    __shared__ __align__(16) f16 Bh[128*64];
    const int tid = threadIdx.x;
    const int w = tid >> 6, lane = tid & 63;
    const int wr = w >> 1, wcc = w & 1;
    const int lr = lane & 15, hi = lane >> 4;

    const int bx = blockIdx.x;
    const f16 *A, *Bt;
    int bm, bn, qside;
    if (bx < 96) { qside = 1; bm = bx / 24; bn = bx % 24; A = Aq; Bt = Wq; }
    else         { qside = 0; const int ix = bx - 96; bm = ix >> 4; bn = ix & 15; A = Ac; Bt = Wc; }

    const int lr8   = lane >> 3;              // row within 8-row group
    const int lslot = (lane & 7) ^ lr8;       // inverse-swizzled 16B slot for staging
    const f16* Ag = A  + (size_t)(bm*128 + w*32) * 1024;
    const f16* Bg = Bt + (size_t)(bn*128 + w*32) * 1024;
    f16* AhW = &Ah[(w*32)*64];
    f16* BhW = &Bh[(w*32)*64];

    f32x4 acc[4][4] = {};

    for (int k0 = 0; k0 < 1024; k0 += 64) {
        #pragma unroll
        for (int i = 0; i < 4; i++) {
            gload16(Ag + (size_t)(i*8 + lr8)*1024 + k0 + lslot*8, AhW + i*8*64);
            gload16(Bg + (size_t)(i*8 + lr8)*1024 + k0 + lslot*8, BhW + i*8*64);
        }
        __syncthreads();
        #pragma unroll
        for (int ks = 0; ks < 2; ks++) {
            f16x8 a[4], b[4];
            #pragma unroll
            for (int mf = 0; mf < 4; mf++) {
                const int row = wr*64 + mf*16 + lr;
                const int sl  = (ks*4 + hi) ^ (lr & 7);
                a[mf] = *(const f16x8*)&Ah[row*64 + sl*8];
            }
            #pragma unroll
            for (int nf = 0; nf < 4; nf++) {
                const int row = wcc*64 + nf*16 + lr;
                const int sl  = (ks*4 + hi) ^ (lr & 7);
                b[nf] = *(const f16x8*)&Bh[row*64 + sl*8];
            }
            #pragma unroll
            for (int mf = 0; mf < 4; mf++)
                #pragma unroll
                for (int nf = 0; nf < 4; nf++)
                    acc[mf][nf] = __builtin_amdgcn_mfma_f32_16x16x32_f16(a[mf], b[nf], acc[mf][nf], 0, 0, 0);
        }
        __syncthreads();
    }

    const int r0 = hi * 4;
    #pragma unroll
    for (int nf = 0; nf < 4; nf++) {
        const int colg = bn*128 + wcc*64 + nf*16 + lr;
        if (qside) {
            if (bn < 4) {
                const float bv = cb1[colg];
                #pragma unroll
                for (int mf = 0; mf < 4; mf++)
                    #pragma unroll
                    for (int r = 0; r < 4; r++) {
                        const int row = bm*128 + wr*64 + mf*16 + r0 + r;
                        X1[(size_t)row*512 + colg] = gelu_exact(acc[mf][nf][r] + bv);
                    }
            } else if (bn < 8) {
                const int c2 = colg - 512;
                const float bv = lb1[c2];
                #pragma unroll
                for (int mf = 0; mf < 4; mf++)
                    #pragma unroll
                    for (int r = 0; r < 4; r++) {
                        const int row = bm*128 + wr*64 + mf*16 + r0 + r;
                        X2[(size_t)row*512 + c2] = gelu_exact(acc[mf][nf][r] + bv);
                    }
            } else {
                const int c2 = colg - 1024;
                const float bv = tqb[c2];
                #pragma unroll
                for (int mf = 0; mf < 4; mf++)
                    #pragma unroll
                    for (int r = 0; r < 4; r++) {
                        const int row = bm*128 + wr*64 + mf*16 + r0 + r;
                        qh[(size_t)row*2048 + c2] = (f16)(acc[mf][nf][r] + bv);
                    }
            }
        } else {
            const float bv = tcb[colg];
            #pragma unroll
            for (int mf = 0; mf < 4; mf++)
                #pragma unroll
                for (int r = 0; r < 4; r++) {
                    const int row = bm*128 + wr*64 + mf*16 + r0 + r;
                    chh[(size_t)row*2048 + colg] = (f16)(acc[mf][nf][r] + bv);
                }
        }
    }
}

// ---------------- score einsum: score[b,c,q,v] = (qh . ch)/32, masked ----------------
__global__ __launch_bounds__(256) void score_nt(
    const f16* __restrict__ qh, const f16* __restrict__ chh,
    const void* __restrict__ maskp, float* __restrict__ score)
{
    const int bc = blockIdx.z, b = bc >> 1, c = bc & 1;
    const int m0 = blockIdx.x * 64, n0 = blockIdx.y * 64;
    const f16* Aq = qh  + (size_t)b*Qn*2048 + c*1024;
    const f16* Bv = chh + (size_t)b*Ln*2048 + c*1024;

    __shared__ __align__(16) f16 Ah[64][72];
    __shared__ __align__(16) f16 Bh[64][72];
    const int tid = threadIdx.x;
    const int w = tid >> 6, lane = tid & 63;
    const int wr = w >> 1, wc = w & 1;
    const int lr = lane & 15, lk = (lane >> 4) * 8;
    const int rr = tid >> 3, gg = (tid & 7) * 8;

    f32x4 acc[2][2] = {};

    for (int k0 = 0; k0 < 1024; k0 += 64) {
        *(f16x8*)&Ah[rr   ][gg] = *(const f16x8*)(Aq + (size_t)(m0+rr   )*2048 + k0 + gg);
        *(f16x8*)&Ah[rr+32][gg] = *(const f16x8*)(Aq + (size_t)(m0+rr+32)*2048 + k0 + gg);
        *(f16x8*)&Bh[rr   ][gg] = *(const f16x8*)(Bv + (size_t)(n0+rr   )*2048 + k0 + gg);
        *(f16x8*)&Bh[rr+32][gg] = *(const f16x8*)(Bv + (size_t)(n0+rr+32)*2048 + k0 + gg);
        __syncthreads();
        #pragma unroll
        for (int ks=0; ks<64; ks+=32){
            f16x8 a[2], b[2];
            #pragma unroll
            for (int mf=0; mf<2; mf++) a[mf] = *(f16x8*)&Ah[wr*32+mf*16+lr][ks+lk];
            #pragma unroll
            for (int nf=0; nf<2; nf++) b[nf] = *(f16x8*)&Bh[wc*32+nf*16+lr][ks+lk];
            #pragma unroll
            for (int mf=0; mf<2; mf++)
                #pragma unroll
                for (int nf=0; nf<2; nf++)
                    acc[mf][nf] = __builtin_amdgcn_mfma_f32_16x16x32_f16(a[mf], b[nf], acc[mf][nf], 0, 0, 0);
        }
        __syncthreads();
    }

    const unsigned u0 = *(const unsigned*)maskp;
    const int r0 = (lane >> 4) * 4;
    #pragma unroll
    for (int nf=0; nf<2; nf++){
        const int v = n0 + wc*32 + nf*16 + lr;
        const bool mv = mask_at(maskp, b*Ln + v, u0);
        #pragma unroll
        for (int mf=0; mf<2; mf++){
            #pragma unroll
            for (int r=0; r<4; r++){
                const int q = m0 + wr*32 + mf*16 + r0 + r;
                float val = mv ? (acc[mf][nf][r] * 0.03125f) : -100000000.0f;
                score[((size_t)(b*2+c)*Qn + q)*Ln + v] = val;
            }
        }
    }
}

// ---------------- fused heads: blocks 0..511 cls softmax, 512..1023 loc geo ----------------
__global__ __launch_bounds__(256) void heads(
    const float* __restrict__ X1, const float* __restrict__ cls_w2,
    const float* __restrict__ cls_b2, const float* __restrict__ qlog, float* __restrict__ out0,
    const float* __restrict__ X2, const float* __restrict__ loc_w2,
    const float* __restrict__ loc_b2, const float* __restrict__ qlocs, float* __restrict__ geo)
{
    const int blk = blockIdx.x, t = threadIdx.x;
    __shared__ float xr[512];
    __shared__ float lg[64];
    __shared__ float mx_s, si_s;
    if (blk < 512) {
        const int row = blk;
        xr[t]       = X1[(size_t)row*512 + t];
        xr[t + 256] = X1[(size_t)row*512 + t + 256];
        __syncthreads();
        const int c = t >> 2, s = t & 3;
        float acc = 0.0f;
        if (c < LBL){
            for (int k = s*128; k < (s+1)*128; k++) acc += xr[k] * cls_w2[(size_t)k*LBL + c];
        }
        acc += __shfl_down(acc, 1);
        acc += __shfl_down(acc, 2);
        if (s == 0 && c < LBL) lg[c] = acc + cls_b2[c] + qlog[(size_t)row*LBL + c];
        __syncthreads();
        if (t == 0){
            float mx = -1e30f;
            for (int k=0;k<LBL;k++) mx = fmaxf(mx, lg[k]);
            float sm = 0.0f;
            for (int k=0;k<LBL;k++) sm += __expf(lg[k]-mx);
            mx_s = mx; si_s = 1.0f / sm;
        }
        __syncthreads();
        if (t < LBL) out0[(size_t)row*LBL + t] = __expf(lg[t]-mx_s) * si_s;
    } else {
        const int row = blk - 512;
        xr[t]       = X2[(size_t)row*512 + t];
        xr[t + 256] = X2[(size_t)row*512 + t + 256];
        __syncthreads();
        const int c = t >> 5, s = t & 31;
        float acc = 0.0f;
        if (c < 6){
            for (int k = s*16; k < (s+1)*16; k++) acc += xr[k] * loc_w2[(size_t)k*6 + c];
        }
        #pragma unroll
        for (int off=1; off<32; off<<=1) acc += __shfl_down(acc, off);
        if (s == 0 && c < 6) lg[c] = acc + loc_b2[c];
        __syncthreads();
        if (t == 0){
            const float o0=lg[0], o1=lg[1], f0=lg[2], f1=lg[3], f2=lg[4], f3=lg[5];
            geo[(size_t)row*5+0] = qlocs[(size_t)row*2+0] + o0;
            geo[(size_t)row*5+1] = qlocs[(size_t)row*2+1] + o1;
            geo[(size_t)row*5+2] = f0*f0 + f1*f1;
            geo[(size_t)row*5+3] = f0*f2 + f1*f3;
            geo[(size_t)row*5+4] = f2*f2 + f3*f3;
        }
    }
}

__device__ __forceinline__ float pair_e(int p, const float* s0, const float* s1,
                                        float m, float c0, float c1,
                                        float F00, float F01, float F11){
    const float sq = sqrtf((float)(263169 - 8*p));
    const int i = (int)((513.0f - sq) * 0.5f);
    const int j = i + (p - ((i*(513 - i)) >> 1));
    const float d0 = (float)i - c0, d1 = (float)j - c1;
    const float quad = fmaf(fmaf(F11, d1, 2.0f*F01*d0), d1, F00*d0*d0);
    return __expf(s0[i] + s1[j] - m - quad);
}

// ---------------- pair reduce: per (bq, slice) partial sums; slice 0 stores m ----------------
__global__ __launch_bounds__(256) void pair_reduce(
    const float* __restrict__ score, const float* __restrict__ geo,
    float* __restrict__ sums, float* __restrict__ mvals)
{
    const int bq = blockIdx.x, sl = blockIdx.y;
    const int b = bq >> 7, t = threadIdx.x;
    __shared__ float s0[256], s1[256], sfx[256], red[256];

    const float* sc0 = score + ((size_t)(b*2+0)*Qn + (bq & 127))*Ln;
    const float* sc1 = sc0 + (size_t)Qn*Ln;
    s0[t] = sc0[t]; s1[t] = sc1[t]; sfx[t] = s1[t];
    __syncthreads();

    for (int off=1; off<256; off<<=1){
        float v = sfx[t];
        if (t + off < 256) v = fmaxf(v, sfx[t+off]);
        __syncthreads();
        sfx[t] = v;
        __syncthreads();
    }
    red[t] = s0[t] + sfx[t];
    __syncthreads();
    for (int off=128; off>0; off>>=1){
        if (t < off) red[t] = fmaxf(red[t], red[t+off]);
        __syncthreads();
    }
    const float m = red[0];
    __syncthreads();

    const float c0  = geo[(size_t)bq*5+0], c1  = geo[(size_t)bq*5+1];
    const float F00 = geo[(size_t)bq*5+2], F01 = geo[(size_t)bq*5+3], F11 = geo[(size_t)bq*5+4];

    const int base = sl * SLICE, end = base + SLICE;
    float lsum = 0.0f;
    for (int p = base + t; p < end; p += 256)
        lsum += pair_e(p, s0, s1, m, c0, c1, F00, F01, F11);
    __syncthreads();
    red[t] = lsum;
    __syncthreads();
    for (int off=128; off>0; off>>=1){
        if (t < off) red[t] += red[t+off];
        __syncthreads();
    }
    if (t == 0){
        sums[bq*8 + sl] = red[0];
        if (sl == 0) mvals[bq] = m;
    }
}

// ---------------- pair write: normalize + store slice (float2 vectorized) ----------------
__global__ __launch_bounds__(256) void pair_write(
    const float* __restrict__ score, const float* __restrict__ geo,
    const float* __restrict__ sums, const float* __restrict__ mvals,
    float* __restrict__ out1)
{
    const int bq = blockIdx.x, sl = blockIdx.y;
    const int b = bq >> 7, t = threadIdx.x;
    __shared__ float s0[256], s1[256];
    __shared__ float invs;

    const float* sc0 = score + ((size_t)(b*2+0)*Qn + (bq & 127))*Ln;
    const float* sc1 = sc0 + (size_t)Qn*Ln;
    s0[t] = sc0[t]; s1[t] = sc1[t];
    if (t == 0){
        float tot = 0.0f;
        #pragma unroll
        for (int k=0;k<8;k++) tot += sums[bq*8 + k];
        invs = 1.0f / (tot + 1e-12f);
    }
    __syncthreads();

    const float m = mvals[bq];
    const float inv = invs;
    const float c0  = geo[(size_t)bq*5+0], c1  = geo[(size_t)bq*5+1];
    const float F00 = geo[(size_t)bq*5+2], F01 = geo[(size_t)bq*5+3], F11 = geo[(size_t)bq*5+4];

    float* op = out1 + (size_t)bq * POUT;
    const int base = sl * SLICE;
    #pragma unroll 2
    for (int it = 0; it < 8; it++){
        const int p = base + it*512 + 2*t;
        const float e0 = pair_e(p,   s0, s1, m, c0, c1, F00, F01, F11);
        const float e1 = pair_e(p+1, s0, s1, m, c0, c1, F00, F01, F11);
        *(float2*)&op[p] = make_float2(e0*inv, e1*inv);
    }
    if (t < 8){
        const int p = base + 4096 + 2*t;
        const float e0 = pair_e(p,   s0, s1, m, c0, c1, F00, F01, F11);
        const float e1 = pair_e(p+1, s0, s1, m, c0, c1, F00, F01, F11);
        *(float2*)&op[p] = make_float2(e0*inv, e1*inv);
    }
}

extern "C" void kernel_launch(void* const* d_in, const int* in_sizes, int n_in,
                              void* d_out, int out_size, void* d_ws, size_t ws_size,
                              hipStream_t stream)
{
    const float* hiddens = (const float*)d_in[0];
    const void*  masks   = d_in[1];
    const float* queries = (const float*)d_in[2];
    const float* qlocs   = (const float*)d_in[3];
    const float* qlogits = (const float*)d_in[4];
    const float* cls_w1  = (const float*)d_in[5];
    const float* cls_b1  = (const float*)d_in[6];
    const float* cls_w2  = (const float*)d_in[7];
    const float* cls_b2  = (const float*)d_in[8];
    const float* tq_w    = (const float*)d_in[9];
    const float* tq_b    = (const float*)d_in[10];
    const float* tc_w    = (const float*)d_in[11];
    const float* tc_b    = (const float*)d_in[12];
    const float* loc_w1  = (const float*)d_in[13];
    const float* loc_b1  = (const float*)d_in[14];
    const float* loc_w2  = (const float*)d_in[15];
    const float* loc_b2  = (const float*)d_in[16];

    char* ws = (char*)d_ws;
    f16*   qf16  = (f16*)  (ws);                     // 1 MB  (512x1024)
    f16*   hf16  = (f16*)  (ws + (1u<<20));          // 2 MB  (1024x1024)
    float* X1    = (float*)(ws + (3u<<20));          // 1 MB  (512x512)
    float* X2    = (float*)(ws + (4u<<20));          // 1 MB
    f16*   qh    = (f16*)  (ws + (5u<<20));          // 2 MB  (512x2048)
    float* score = (float*)(ws + (7u<<20));          // 1 MB  (B,2,Q,L)
    float* geo   = (float*)(ws + (8u<<20));          // 10 KB
    float* sums  = (float*)(ws + (8u<<20) + 0x4000); // 16 KB
    float* mvals = (float*)(ws + (8u<<20) + 0x8000); // 2 KB

    float* out0 = (float*)d_out;
    float* out1 = out0 + (size_t)Bn*Qn*LBL;

    // big transient scratch inside out1 (fully overwritten by pair_write at the end)
    f16* Wq_t = (f16*)out1;                                   // 3072x1024 f16 = 6 MB
    f16* Wc_t = (f16*)((char*)out1 + 6291456);                // 2048x1024 f16 = 4 MB
    f16* chh  = (f16*)((char*)out1 + 6291456 + 4194304);      // 1024x2048 f16 = 4 MB

    prep<<<dim3(6656), 256, 0, stream>>>(queries, hiddens, cls_w1, loc_w1, tq_w, tc_w,
                                         qf16, hf16, Wq_t, Wc_t);
    gemm128<<<dim3(224), 256, 0, stream>>>(qf16, hf16, Wq_t, Wc_t,
                                           cls_b1, loc_b1, tq_b, tc_b,
                                           X1, X2, qh, chh);
    score_nt<<<dim3(2, 4, 8), 256, 0, stream>>>(qh, chh, masks, score);
    heads   <<<dim3(1024), 256, 0, stream>>>(X1, cls_w2, cls_b2, qlogits, out0,
                                             X2, loc_w2, loc_b2, qlocs, geo);
    pair_reduce<<<dim3(Bn*Qn, 8), 256, 0, stream>>>(score, geo, sums, mvals);
    pair_write <<<dim3(Bn*Qn, 8), 256, 0, stream>>>(score, geo, sums, mvals, out1);
}

// Round 4
// 95.585 us; speedup vs baseline: 2.2091x; 1.2866x over previous
//
#include <hip/hip_runtime.h>
#include <math.h>

typedef _Float16 f16;
typedef __attribute__((ext_vector_type(4))) _Float16 f16x4;
typedef __attribute__((ext_vector_type(8))) _Float16 f16x8;
typedef __attribute__((ext_vector_type(4))) float f32x4;

#define Bn 4
#define Ln 256
#define Qn 128
#define Hn 1024
#define LBL 33
#define POUT 32896   // 256*257/2

__device__ __forceinline__ float gelu_exact(float x){
    return 0.5f * x * (1.0f + erff(x * 0.70710678118654752f));
}

__device__ __forceinline__ bool mask_at(const void* m, int idx, unsigned u0){
    if (u0 == 0x01010101u) return ((const unsigned char*)m)[idx] != 0;
    if (u0 == 0x3f800000u) return ((const float*)m)[idx] != 0.0f;
    return ((const int*)m)[idx] != 0;
}

__device__ __forceinline__ void gload16(const void* g, void* l){
    __builtin_amdgcn_global_load_lds(
        (const __attribute__((address_space(1))) unsigned int*)g,
        (__attribute__((address_space(3))) unsigned int*)l, 16, 0, 0);
}

// ---------------- prep: input f32->f16 cvt + weight cvt/transpose ----------------
__global__ __launch_bounds__(256) void prep(
    const float* __restrict__ q, const float* __restrict__ h,
    const float* __restrict__ cls_w1, const float* __restrict__ loc_w1,
    const float* __restrict__ tq_w,  const float* __restrict__ tc_w,
    f16* __restrict__ qf, f16* __restrict__ hf,
    f16* __restrict__ Wq_t, f16* __restrict__ Wc_t)
{
    const int bx = blockIdx.x, t = threadIdx.x;
    if (bx < 1536) {
        if (bx < 512) {
            const int gid = bx*256 + t;
            const float4 v = ((const float4*)q)[gid];
            f16x4 o; o[0]=(f16)v.x; o[1]=(f16)v.y; o[2]=(f16)v.z; o[3]=(f16)v.w;
            *(f16x4*)&qf[(size_t)gid*4] = o;
        } else {
            const int gid = (bx-512)*256 + t;
            const float4 v = ((const float4*)h)[gid];
            f16x4 o; o[0]=(f16)v.x; o[1]=(f16)v.y; o[2]=(f16)v.z; o[3]=(f16)v.w;
            *(f16x4*)&hf[(size_t)gid*4] = o;
        }
        return;
    }
    const int tile = bx - 1536;     // 0..5119
    const float* src; f16* dst; int id, lg;
    if      (tile < 512)  { id = tile;        src = cls_w1; dst = Wq_t;                        lg = 4; }
    else if (tile < 1024) { id = tile - 512;  src = loc_w1; dst = Wq_t + (size_t)512*1024;     lg = 4; }
    else if (tile < 3072) { id = tile - 1024; src = tq_w;   dst = Wq_t + (size_t)1024*1024;    lg = 6; }
    else                  { id = tile - 3072; src = tc_w;   dst = Wc_t;                        lg = 6; }
    const int N  = 32 << lg;
    const int n0 = (id & ((1<<lg)-1)) * 32;
    const int k0 = (id >> lg) * 32;

    __shared__ f16 T[32][36];
    const int r = t >> 3, c4 = (t & 7) * 4;
    const float4 v = *(const float4*)&src[(size_t)(k0 + r) * N + n0 + c4];
    T[c4+0][r] = (f16)v.x; T[c4+1][r] = (f16)v.y;
    T[c4+2][r] = (f16)v.z; T[c4+3][r] = (f16)v.w;
    __syncthreads();
    f16x4 o;
    o[0] = T[t>>3][(t&7)*4+0]; o[1] = T[t>>3][(t&7)*4+1];
    o[2] = T[t>>3][(t&7)*4+2]; o[3] = T[t>>3][(t&7)*4+3];
    *(f16x4*)&dst[(size_t)(n0 + (t>>3)) * 1024 + k0 + (t&7)*4] = o;
}

// ---------------- fused 128x128-tile GEMM (m97 structure), K=1024 ----------------
__global__ __launch_bounds__(256) void gemm128(
    const f16* __restrict__ Aq, const f16* __restrict__ Ac,
    const f16* __restrict__ Wq, const f16* __restrict__ Wc,
    const float* __restrict__ cb1, const float* __restrict__ lb1,
    const float* __restrict__ tqb, const float* __restrict__ tcb,
    float* __restrict__ X1, float* __restrict__ X2,
    f16* __restrict__ qh, f16* __restrict__ chh)
{
    __shared__ __align__(16) f16 Ah[128*64];
    __shared__ __align__(16) f16 Bh[128*64];
    const int tid = threadIdx.x;
    const int w = tid >> 6, lane = tid & 63;
    const int wr = w >> 1, wcc = w & 1;
    const int lr = lane & 15, hi = lane >> 4;

    const int bx = blockIdx.x;
    const f16 *A, *Bt;
    int bm, bn, qside;
    if (bx < 96) { qside = 1; bm = bx / 24; bn = bx % 24; A = Aq; Bt = Wq; }
    else         { qside = 0; const int ix = bx - 96; bm = ix >> 4; bn = ix & 15; A = Ac; Bt = Wc; }

    const int lr8   = lane >> 3;
    const int lslot = (lane & 7) ^ lr8;
    const f16* Ag = A  + (size_t)(bm*128 + w*32) * 1024;
    const f16* Bg = Bt + (size_t)(bn*128 + w*32) * 1024;
    f16* AhW = &Ah[(w*32)*64];
    f16* BhW = &Bh[(w*32)*64];

    f32x4 acc[4][4] = {};

    for (int k0 = 0; k0 < 1024; k0 += 64) {
        #pragma unroll
        for (int i = 0; i < 4; i++) {
            gload16(Ag + (size_t)(i*8 + lr8)*1024 + k0 + lslot*8, AhW + i*8*64);
            gload16(Bg + (size_t)(i*8 + lr8)*1024 + k0 + lslot*8, BhW + i*8*64);
        }
        __syncthreads();
        #pragma unroll
        for (int ks = 0; ks < 2; ks++) {
            f16x8 a[4], b[4];
            #pragma unroll
            for (int mf = 0; mf < 4; mf++) {
                const int row = wr*64 + mf*16 + lr;
                const int sl  = (ks*4 + hi) ^ (lr & 7);
                a[mf] = *(const f16x8*)&Ah[row*64 + sl*8];
            }
            #pragma unroll
            for (int nf = 0; nf < 4; nf++) {
                const int row = wcc*64 + nf*16 + lr;
                const int sl  = (ks*4 + hi) ^ (lr & 7);
                b[nf] = *(const f16x8*)&Bh[row*64 + sl*8];
            }
            #pragma unroll
            for (int mf = 0; mf < 4; mf++)
                #pragma unroll
                for (int nf = 0; nf < 4; nf++)
                    acc[mf][nf] = __builtin_amdgcn_mfma_f32_16x16x32_f16(a[mf], b[nf], acc[mf][nf], 0, 0, 0);
        }
        __syncthreads();
    }

    const int r0 = hi * 4;
    #pragma unroll
    for (int nf = 0; nf < 4; nf++) {
        const int colg = bn*128 + wcc*64 + nf*16 + lr;
        if (qside) {
            if (bn < 4) {
                const float bv = cb1[colg];
                #pragma unroll
                for (int mf = 0; mf < 4; mf++)
                    #pragma unroll
                    for (int r = 0; r < 4; r++) {
                        const int row = bm*128 + wr*64 + mf*16 + r0 + r;
                        X1[(size_t)row*512 + colg] = gelu_exact(acc[mf][nf][r] + bv);
                    }
            } else if (bn < 8) {
                const int c2 = colg - 512;
                const float bv = lb1[c2];
                #pragma unroll
                for (int mf = 0; mf < 4; mf++)
                    #pragma unroll
                    for (int r = 0; r < 4; r++) {
                        const int row = bm*128 + wr*64 + mf*16 + r0 + r;
                        X2[(size_t)row*512 + c2] = gelu_exact(acc[mf][nf][r] + bv);
                    }
            } else {
                const int c2 = colg - 1024;
                const float bv = tqb[c2];
                #pragma unroll
                for (int mf = 0; mf < 4; mf++)
                    #pragma unroll
                    for (int r = 0; r < 4; r++) {
                        const int row = bm*128 + wr*64 + mf*16 + r0 + r;
                        qh[(size_t)row*2048 + c2] = (f16)(acc[mf][nf][r] + bv);
                    }
            }
        } else {
            const float bv = tcb[colg];
            #pragma unroll
            for (int mf = 0; mf < 4; mf++)
                #pragma unroll
                for (int r = 0; r < 4; r++) {
                    const int row = bm*128 + wr*64 + mf*16 + r0 + r;
                    chh[(size_t)row*2048 + colg] = (f16)(acc[mf][nf][r] + bv);
                }
        }
    }
}

// ---------------- fused: blocks [0,64) score einsum ; [64,576) cls softmax ; [576,1088) loc geo ----------------
__global__ __launch_bounds__(256) void score_heads(
    const f16* __restrict__ qh, const f16* __restrict__ chh,
    const void* __restrict__ maskp, float* __restrict__ score,
    const float* __restrict__ X1, const float* __restrict__ cls_w2,
    const float* __restrict__ cls_b2, const float* __restrict__ qlog, float* __restrict__ out0,
    const float* __restrict__ X2, const float* __restrict__ loc_w2,
    const float* __restrict__ loc_b2, const float* __restrict__ qlocs, float* __restrict__ geo)
{
    __shared__ __align__(16) char smem[64*72*2*2 + 64];
    const int bx = blockIdx.x, tid = threadIdx.x;

    if (bx < 64) {
        // ----- score path -----
        f16* Ah = (f16*)smem;             // [64][72]
        f16* Bh = Ah + 64*72;
        const int bc = bx & 7, b = bc >> 1, c = bc & 1;
        const int n0 = ((bx >> 3) & 3) * 64;
        const int m0 = (bx >> 5) * 64;
        const f16* Aq = qh  + (size_t)b*Qn*2048 + c*1024;
        const f16* Bv = chh + (size_t)b*Ln*2048 + c*1024;

        const int w = tid >> 6, lane = tid & 63;
        const int wr = w >> 1, wc = w & 1;
        const int lr = lane & 15, lk = (lane >> 4) * 8;
        const int rr = tid >> 3, gg = (tid & 7) * 8;

        f32x4 acc[2][2] = {};

        for (int k0 = 0; k0 < 1024; k0 += 64) {
            *(f16x8*)&Ah[(rr   )*72 + gg] = *(const f16x8*)(Aq + (size_t)(m0+rr   )*2048 + k0 + gg);
            *(f16x8*)&Ah[(rr+32)*72 + gg] = *(const f16x8*)(Aq + (size_t)(m0+rr+32)*2048 + k0 + gg);
            *(f16x8*)&Bh[(rr   )*72 + gg] = *(const f16x8*)(Bv + (size_t)(n0+rr   )*2048 + k0 + gg);
            *(f16x8*)&Bh[(rr+32)*72 + gg] = *(const f16x8*)(Bv + (size_t)(n0+rr+32)*2048 + k0 + gg);
            __syncthreads();
            #pragma unroll
            for (int ks=0; ks<64; ks+=32){
                f16x8 a[2], b2[2];
                #pragma unroll
                for (int mf=0; mf<2; mf++) a[mf]  = *(f16x8*)&Ah[(wr*32+mf*16+lr)*72 + ks+lk];
                #pragma unroll
                for (int nf=0; nf<2; nf++) b2[nf] = *(f16x8*)&Bh[(wc*32+nf*16+lr)*72 + ks+lk];
                #pragma unroll
                for (int mf=0; mf<2; mf++)
                    #pragma unroll
                    for (int nf=0; nf<2; nf++)
                        acc[mf][nf] = __builtin_amdgcn_mfma_f32_16x16x32_f16(a[mf], b2[nf], acc[mf][nf], 0, 0, 0);
            }
            __syncthreads();
        }

        const unsigned u0 = *(const unsigned*)maskp;
        const int r0 = (lane >> 4) * 4;
        #pragma unroll
        for (int nf=0; nf<2; nf++){
            const int v = n0 + wc*32 + nf*16 + lr;
            const bool mv = mask_at(maskp, b*Ln + v, u0);
            #pragma unroll
            for (int mf=0; mf<2; mf++){
                #pragma unroll
                for (int r=0; r<4; r++){
                    const int q = m0 + wr*32 + mf*16 + r0 + r;
                    float val = mv ? (acc[mf][nf][r] * 0.03125f) : -100000000.0f;
                    score[((size_t)(b*2+c)*Qn + q)*Ln + v] = val;
                }
            }
        }
    } else if (bx < 576) {
        // ----- cls softmax path -----
        float* xr = (float*)smem;         // 512
        float* lg = xr + 512;             // 64
        float* sc = lg + 64;              // 2
        const int row = bx - 64, t = tid;
        xr[t]       = X1[(size_t)row*512 + t];
        xr[t + 256] = X1[(size_t)row*512 + t + 256];
        __syncthreads();
        const int c = t >> 2, s = t & 3;
        float acc = 0.0f;
        if (c < LBL){
            for (int k = s*128; k < (s+1)*128; k++) acc += xr[k] * cls_w2[(size_t)k*LBL + c];
        }
        acc += __shfl_down(acc, 1);
        acc += __shfl_down(acc, 2);
        if (s == 0 && c < LBL) lg[c] = acc + cls_b2[c] + qlog[(size_t)row*LBL + c];
        __syncthreads();
        if (t == 0){
            float mx = -1e30f;
            for (int k=0;k<LBL;k++) mx = fmaxf(mx, lg[k]);
            float sm = 0.0f;
            for (int k=0;k<LBL;k++) sm += __expf(lg[k]-mx);
            sc[0] = mx; sc[1] = 1.0f / sm;
        }
        __syncthreads();
        if (t < LBL) out0[(size_t)row*LBL + t] = __expf(lg[t]-sc[0]) * sc[1];
    } else {
        // ----- loc geo path -----
        float* xr = (float*)smem;
        float* lg = xr + 512;
        const int row = bx - 576, t = tid;
        xr[t]       = X2[(size_t)row*512 + t];
        xr[t + 256] = X2[(size_t)row*512 + t + 256];
        __syncthreads();
        const int c = t >> 5, s = t & 31;
        float acc = 0.0f;
        if (c < 6){
            for (int k = s*16; k < (s+1)*16; k++) acc += xr[k] * loc_w2[(size_t)k*6 + c];
        }
        #pragma unroll
        for (int off=1; off<32; off<<=1) acc += __shfl_down(acc, off);
        if (s == 0 && c < 6) lg[c] = acc + loc_b2[c];
        __syncthreads();
        if (t == 0){
            const float o0=lg[0], o1=lg[1], f0=lg[2], f1=lg[3], f2=lg[4], f3=lg[5];
            geo[(size_t)row*5+0] = qlocs[(size_t)row*2+0] + o0;
            geo[(size_t)row*5+1] = qlocs[(size_t)row*2+1] + o1;
            geo[(size_t)row*5+2] = f0*f0 + f1*f1;
            geo[(size_t)row*5+3] = f0*f2 + f1*f3;
            geo[(size_t)row*5+4] = f2*f2 + f3*f3;
        }
    }
}

// ---------------- pair softmax, single pass: e kept in registers ----------------
__global__ __launch_bounds__(1024) void pair_fused(
    const float* __restrict__ score, const float* __restrict__ geo,
    float* __restrict__ out1)
{
    const int bq = blockIdx.x, b = bq >> 7, t = threadIdx.x;
    __shared__ float s0[256], s1[256];
    __shared__ float red[16];
    __shared__ float bcast;

    const float* sc0 = score + ((size_t)(b*2)*Qn + (bq & 127))*Ln;
    if (t < 256)      s0[t]       = sc0[t];
    else if (t < 512) s1[t - 256] = sc0[(size_t)Qn*Ln + (t - 256)];
    __syncthreads();

    const float c0  = geo[(size_t)bq*5+0], c1  = geo[(size_t)bq*5+1];
    const float F00 = geo[(size_t)bq*5+2], F01 = geo[(size_t)bq*5+3], F11 = geo[(size_t)bq*5+4];

    // phase A: decode + s-value into registers, track max of (s0+s1)
    float sval[33];
    float lmax = -3.0e38f;
    #pragma unroll
    for (int k = 0; k < 33; k++) {
        const int p = k*1024 + t;
        if (k < 32 || p < POUT) {
            const float sq = sqrtf((float)(263169 - 8*p));
            const int i = (int)((513.0f - sq) * 0.5f);
            const int j = i + (p - ((i*(513 - i)) >> 1));
            const float s = s0[i] + s1[j];
            const float d0 = (float)i - c0, d1 = (float)j - c1;
            const float quad = fmaf(fmaf(F11, d1, 2.0f*F01*d0), d1, F00*d0*d0);
            sval[k] = s - quad;
            lmax = fmaxf(lmax, s);
        } else {
            sval[k] = -3.0e38f;
        }
    }

    // block max
    #pragma unroll
    for (int off = 1; off < 64; off <<= 1) lmax = fmaxf(lmax, __shfl_xor(lmax, off));
    if ((t & 63) == 0) red[t >> 6] = lmax;
    __syncthreads();
    if (t == 0) {
        float v = red[0];
        #pragma unroll
        for (int k = 1; k < 16; k++) v = fmaxf(v, red[k]);
        bcast = v;
    }
    __syncthreads();
    const float m = bcast;

    // phase B: exp in registers + block sum
    float lsum = 0.0f;
    #pragma unroll
    for (int k = 0; k < 33; k++) {
        sval[k] = __expf(sval[k] - m);
        lsum += sval[k];
    }
    #pragma unroll
    for (int off = 1; off < 64; off <<= 1) lsum += __shfl_xor(lsum, off);
    __syncthreads();          // red[] reuse safe-guard
    if ((t & 63) == 0) red[t >> 6] = lsum;
    __syncthreads();
    if (t == 0) {
        float v = 0.0f;
        #pragma unroll
        for (int k = 0; k < 16; k++) v += red[k];
        bcast = 1.0f / (v + 1e-12f);
    }
    __syncthreads();
    const float inv = bcast;

    // phase C: normalized coalesced stores
    float* op = out1 + (size_t)bq * POUT;
    #pragma unroll
    for (int k = 0; k < 32; k++) op[k*1024 + t] = sval[k] * inv;
    if (t < 128) op[32768 + t] = sval[32] * inv;
}

extern "C" void kernel_launch(void* const* d_in, const int* in_sizes, int n_in,
                              void* d_out, int out_size, void* d_ws, size_t ws_size,
                              hipStream_t stream)
{
    const float* hiddens = (const float*)d_in[0];
    const void*  masks   = d_in[1];
    const float* queries = (const float*)d_in[2];
    const float* qlocs   = (const float*)d_in[3];
    const float* qlogits = (const float*)d_in[4];
    const float* cls_w1  = (const float*)d_in[5];
    const float* cls_b1  = (const float*)d_in[6];
    const float* cls_w2  = (const float*)d_in[7];
    const float* cls_b2  = (const float*)d_in[8];
    const float* tq_w    = (const float*)d_in[9];
    const float* tq_b    = (const float*)d_in[10];
    const float* tc_w    = (const float*)d_in[11];
    const float* tc_b    = (const float*)d_in[12];
    const float* loc_w1  = (const float*)d_in[13];
    const float* loc_b1  = (const float*)d_in[14];
    const float* loc_w2  = (const float*)d_in[15];
    const float* loc_b2  = (const float*)d_in[16];

    char* ws = (char*)d_ws;
    f16*   qf16  = (f16*)  (ws);                     // 1 MB  (512x1024)
    f16*   hf16  = (f16*)  (ws + (1u<<20));          // 2 MB  (1024x1024)
    float* X1    = (float*)(ws + (3u<<20));          // 1 MB  (512x512)
    float* X2    = (float*)(ws + (4u<<20));          // 1 MB
    f16*   qh    = (f16*)  (ws + (5u<<20));          // 2 MB  (512x2048)
    float* score = (float*)(ws + (7u<<20));          // 1 MB  (B,2,Q,L)
    float* geo   = (float*)(ws + (8u<<20));          // 10 KB

    float* out0 = (float*)d_out;
    float* out1 = out0 + (size_t)Bn*Qn*LBL;

    // big transient scratch inside out1 (fully overwritten by pair_fused at the end)
    f16* Wq_t = (f16*)out1;                                   // 3072x1024 f16 = 6 MB
    f16* Wc_t = (f16*)((char*)out1 + 6291456);                // 2048x1024 f16 = 4 MB
    f16* chh  = (f16*)((char*)out1 + 6291456 + 4194304);      // 1024x2048 f16 = 4 MB

    prep<<<dim3(6656), 256, 0, stream>>>(queries, hiddens, cls_w1, loc_w1, tq_w, tc_w,
                                         qf16, hf16, Wq_t, Wc_t);
    gemm128<<<dim3(224), 256, 0, stream>>>(qf16, hf16, Wq_t, Wc_t,
                                           cls_b1, loc_b1, tq_b, tc_b,
                                           X1, X2, qh, chh);
    score_heads<<<dim3(1088), 256, 0, stream>>>(qh, chh, masks, score,
                                                X1, cls_w2, cls_b2, qlogits, out0,
                                                X2, loc_w2, loc_b2, qlocs, geo);
    pair_fused<<<dim3(Bn*Qn), 1024, 0, stream>>>(score, geo, out1);
}

// Round 5
// 88.224 us; speedup vs baseline: 2.3935x; 1.0834x over previous
//
#include <hip/hip_runtime.h>
#include <math.h>

typedef _Float16 f16;
typedef __attribute__((ext_vector_type(4))) _Float16 f16x4;
typedef __attribute__((ext_vector_type(8))) _Float16 f16x8;
typedef __attribute__((ext_vector_type(4))) float f32x4;

#define Bn 4
#define Ln 256
#define Qn 128
#define Hn 1024
#define LBL 33
#define POUT 32896   // 256*257/2

__device__ __forceinline__ float gelu_exact(float x){
    return 0.5f * x * (1.0f + erff(x * 0.70710678118654752f));
}

__device__ __forceinline__ bool mask_at(const void* m, int idx, unsigned u0){
    if (u0 == 0x01010101u) return ((const unsigned char*)m)[idx] != 0;
    if (u0 == 0x3f800000u) return ((const float*)m)[idx] != 0.0f;
    return ((const int*)m)[idx] != 0;
}

__device__ __forceinline__ void gload16(const void* g, void* l){
    __builtin_amdgcn_global_load_lds(
        (const __attribute__((address_space(1))) unsigned int*)g,
        (__attribute__((address_space(3))) unsigned int*)l, 16, 0, 0);
}

// ---------------- prep: input f32->f16 cvt + weight cvt/transpose ----------------
__global__ __launch_bounds__(256) void prep(
    const float* __restrict__ q, const float* __restrict__ h,
    const float* __restrict__ cls_w1, const float* __restrict__ loc_w1,
    const float* __restrict__ tq_w,  const float* __restrict__ tc_w,
    f16* __restrict__ qf, f16* __restrict__ hf,
    f16* __restrict__ Wq_t, f16* __restrict__ Wc_t)
{
    const int bx = blockIdx.x, t = threadIdx.x;
    if (bx < 1536) {
        if (bx < 512) {
            const int gid = bx*256 + t;
            const float4 v = ((const float4*)q)[gid];
            f16x4 o; o[0]=(f16)v.x; o[1]=(f16)v.y; o[2]=(f16)v.z; o[3]=(f16)v.w;
            *(f16x4*)&qf[(size_t)gid*4] = o;
        } else {
            const int gid = (bx-512)*256 + t;
            const float4 v = ((const float4*)h)[gid];
            f16x4 o; o[0]=(f16)v.x; o[1]=(f16)v.y; o[2]=(f16)v.z; o[3]=(f16)v.w;
            *(f16x4*)&hf[(size_t)gid*4] = o;
        }
        return;
    }
    const int tile = bx - 1536;     // 0..5119
    const float* src; f16* dst; int id, lg;
    if      (tile < 512)  { id = tile;        src = cls_w1; dst = Wq_t;                        lg = 4; }
    else if (tile < 1024) { id = tile - 512;  src = loc_w1; dst = Wq_t + (size_t)512*1024;     lg = 4; }
    else if (tile < 3072) { id = tile - 1024; src = tq_w;   dst = Wq_t + (size_t)1024*1024;    lg = 6; }
    else                  { id = tile - 3072; src = tc_w;   dst = Wc_t;                        lg = 6; }
    const int N  = 32 << lg;
    const int n0 = (id & ((1<<lg)-1)) * 32;
    const int k0 = (id >> lg) * 32;

    __shared__ f16 T[32][36];
    const int r = t >> 3, c4 = (t & 7) * 4;
    const float4 v = *(const float4*)&src[(size_t)(k0 + r) * N + n0 + c4];
    T[c4+0][r] = (f16)v.x; T[c4+1][r] = (f16)v.y;
    T[c4+2][r] = (f16)v.z; T[c4+3][r] = (f16)v.w;
    __syncthreads();
    f16x4 o;
    o[0] = T[t>>3][(t&7)*4+0]; o[1] = T[t>>3][(t&7)*4+1];
    o[2] = T[t>>3][(t&7)*4+2]; o[3] = T[t>>3][(t&7)*4+3];
    *(f16x4*)&dst[(size_t)(n0 + (t>>3)) * 1024 + k0 + (t&7)*4] = o;
}

// ---------------- fused 128x128-tile GEMM (m97 structure), K=1024 ----------------
__global__ __launch_bounds__(256) void gemm128(
    const f16* __restrict__ Aq, const f16* __restrict__ Ac,
    const f16* __restrict__ Wq, const f16* __restrict__ Wc,
    const float* __restrict__ cb1, const float* __restrict__ lb1,
    const float* __restrict__ tqb, const float* __restrict__ tcb,
    float* __restrict__ X1, float* __restrict__ X2,
    f16* __restrict__ qh, f16* __restrict__ chh)
{
    __shared__ __align__(16) f16 Ah[128*64];
    __shared__ __align__(16) f16 Bh[128*64];
    const int tid = threadIdx.x;
    const int w = tid >> 6, lane = tid & 63;
    const int wr = w >> 1, wcc = w & 1;
    const int lr = lane & 15, hi = lane >> 4;

    const int bx = blockIdx.x;
    const f16 *A, *Bt;
    int bm, bn, qside;
    if (bx < 96) { qside = 1; bm = bx / 24; bn = bx % 24; A = Aq; Bt = Wq; }
    else         { qside = 0; const int ix = bx - 96; bm = ix >> 4; bn = ix & 15; A = Ac; Bt = Wc; }

    const int lr8   = lane >> 3;
    const int lslot = (lane & 7) ^ lr8;
    const f16* Ag = A  + (size_t)(bm*128 + w*32) * 1024;
    const f16* Bg = Bt + (size_t)(bn*128 + w*32) * 1024;
    f16* AhW = &Ah[(w*32)*64];
    f16* BhW = &Bh[(w*32)*64];

    f32x4 acc[4][4] = {};

    for (int k0 = 0; k0 < 1024; k0 += 64) {
        #pragma unroll
        for (int i = 0; i < 4; i++) {
            gload16(Ag + (size_t)(i*8 + lr8)*1024 + k0 + lslot*8, AhW + i*8*64);
            gload16(Bg + (size_t)(i*8 + lr8)*1024 + k0 + lslot*8, BhW + i*8*64);
        }
        __syncthreads();
        #pragma unroll
        for (int ks = 0; ks < 2; ks++) {
            f16x8 a[4], b[4];
            #pragma unroll
            for (int mf = 0; mf < 4; mf++) {
                const int row = wr*64 + mf*16 + lr;
                const int sl  = (ks*4 + hi) ^ (lr & 7);
                a[mf] = *(const f16x8*)&Ah[row*64 + sl*8];
            }
            #pragma unroll
            for (int nf = 0; nf < 4; nf++) {
                const int row = wcc*64 + nf*16 + lr;
                const int sl  = (ks*4 + hi) ^ (lr & 7);
                b[nf] = *(const f16x8*)&Bh[row*64 + sl*8];
            }
            #pragma unroll
            for (int mf = 0; mf < 4; mf++)
                #pragma unroll
                for (int nf = 0; nf < 4; nf++)
                    acc[mf][nf] = __builtin_amdgcn_mfma_f32_16x16x32_f16(a[mf], b[nf], acc[mf][nf], 0, 0, 0);
        }
        __syncthreads();
    }

    const int r0 = hi * 4;
    #pragma unroll
    for (int nf = 0; nf < 4; nf++) {
        const int colg = bn*128 + wcc*64 + nf*16 + lr;
        if (qside) {
            if (bn < 4) {
                const float bv = cb1[colg];
                #pragma unroll
                for (int mf = 0; mf < 4; mf++)
                    #pragma unroll
                    for (int r = 0; r < 4; r++) {
                        const int row = bm*128 + wr*64 + mf*16 + r0 + r;
                        X1[(size_t)row*512 + colg] = gelu_exact(acc[mf][nf][r] + bv);
                    }
            } else if (bn < 8) {
                const int c2 = colg - 512;
                const float bv = lb1[c2];
                #pragma unroll
                for (int mf = 0; mf < 4; mf++)
                    #pragma unroll
                    for (int r = 0; r < 4; r++) {
                        const int row = bm*128 + wr*64 + mf*16 + r0 + r;
                        X2[(size_t)row*512 + c2] = gelu_exact(acc[mf][nf][r] + bv);
                    }
            } else {
                const int c2 = colg - 1024;
                const float bv = tqb[c2];
                #pragma unroll
                for (int mf = 0; mf < 4; mf++)
                    #pragma unroll
                    for (int r = 0; r < 4; r++) {
                        const int row = bm*128 + wr*64 + mf*16 + r0 + r;
                        qh[(size_t)row*2048 + c2] = (f16)(acc[mf][nf][r] + bv);
                    }
            }
        } else {
            const float bv = tcb[colg];
            #pragma unroll
            for (int mf = 0; mf < 4; mf++)
                #pragma unroll
                for (int r = 0; r < 4; r++) {
                    const int row = bm*128 + wr*64 + mf*16 + r0 + r;
                    chh[(size_t)row*2048 + colg] = (f16)(acc[mf][nf][r] + bv);
                }
        }
    }
}

// ---------------- fused: blocks [0,64) score einsum ; [64,576) cls softmax ; [576,1088) loc geo ----------------
__global__ __launch_bounds__(256) void score_heads(
    const f16* __restrict__ qh, const f16* __restrict__ chh,
    const void* __restrict__ maskp, float* __restrict__ score,
    const float* __restrict__ X1, const float* __restrict__ cls_w2,
    const float* __restrict__ cls_b2, const float* __restrict__ qlog, float* __restrict__ out0,
    const float* __restrict__ X2, const float* __restrict__ loc_w2,
    const float* __restrict__ loc_b2, const float* __restrict__ qlocs, float* __restrict__ geo)
{
    __shared__ __align__(16) char smem[64*72*2*2 + 64];
    const int bx = blockIdx.x, tid = threadIdx.x;

    if (bx < 64) {
        // ----- score path -----
        f16* Ah = (f16*)smem;             // [64][72]
        f16* Bh = Ah + 64*72;
        const int bc = bx & 7, b = bc >> 1, c = bc & 1;
        const int n0 = ((bx >> 3) & 3) * 64;
        const int m0 = (bx >> 5) * 64;
        const f16* Aq = qh  + (size_t)b*Qn*2048 + c*1024;
        const f16* Bv = chh + (size_t)b*Ln*2048 + c*1024;

        const int w = tid >> 6, lane = tid & 63;
        const int wr = w >> 1, wc = w & 1;
        const int lr = lane & 15, lk = (lane >> 4) * 8;
        const int rr = tid >> 3, gg = (tid & 7) * 8;

        f32x4 acc[2][2] = {};

        for (int k0 = 0; k0 < 1024; k0 += 64) {
            *(f16x8*)&Ah[(rr   )*72 + gg] = *(const f16x8*)(Aq + (size_t)(m0+rr   )*2048 + k0 + gg);
            *(f16x8*)&Ah[(rr+32)*72 + gg] = *(const f16x8*)(Aq + (size_t)(m0+rr+32)*2048 + k0 + gg);
            *(f16x8*)&Bh[(rr   )*72 + gg] = *(const f16x8*)(Bv + (size_t)(n0+rr   )*2048 + k0 + gg);
            *(f16x8*)&Bh[(rr+32)*72 + gg] = *(const f16x8*)(Bv + (size_t)(n0+rr+32)*2048 + k0 + gg);
            __syncthreads();
            #pragma unroll
            for (int ks=0; ks<64; ks+=32){
                f16x8 a[2], b2[2];
                #pragma unroll
                for (int mf=0; mf<2; mf++) a[mf]  = *(f16x8*)&Ah[(wr*32+mf*16+lr)*72 + ks+lk];
                #pragma unroll
                for (int nf=0; nf<2; nf++) b2[nf] = *(f16x8*)&Bh[(wc*32+nf*16+lr)*72 + ks+lk];
                #pragma unroll
                for (int mf=0; mf<2; mf++)
                    #pragma unroll
                    for (int nf=0; nf<2; nf++)
                        acc[mf][nf] = __builtin_amdgcn_mfma_f32_16x16x32_f16(a[mf], b2[nf], acc[mf][nf], 0, 0, 0);
            }
            __syncthreads();
        }

        const unsigned u0 = *(const unsigned*)maskp;
        const int r0 = (lane >> 4) * 4;
        #pragma unroll
        for (int nf=0; nf<2; nf++){
            const int v = n0 + wc*32 + nf*16 + lr;
            const bool mv = mask_at(maskp, b*Ln + v, u0);
            #pragma unroll
            for (int mf=0; mf<2; mf++){
                #pragma unroll
                for (int r=0; r<4; r++){
                    const int q = m0 + wr*32 + mf*16 + r0 + r;
                    float val = mv ? (acc[mf][nf][r] * 0.03125f) : -100000000.0f;
                    score[((size_t)(b*2+c)*Qn + q)*Ln + v] = val;
                }
            }
        }
    } else if (bx < 576) {
        // ----- cls softmax path -----
        float* xr = (float*)smem;         // 512
        float* lg = xr + 512;             // 64
        float* sc = lg + 64;              // 2
        const int row = bx - 64, t = tid;
        xr[t]       = X1[(size_t)row*512 + t];
        xr[t + 256] = X1[(size_t)row*512 + t + 256];
        __syncthreads();
        const int c = t >> 2, s = t & 3;
        float acc = 0.0f;
        if (c < LBL){
            for (int k = s*128; k < (s+1)*128; k++) acc += xr[k] * cls_w2[(size_t)k*LBL + c];
        }
        acc += __shfl_down(acc, 1);
        acc += __shfl_down(acc, 2);
        if (s == 0 && c < LBL) lg[c] = acc + cls_b2[c] + qlog[(size_t)row*LBL + c];
        __syncthreads();
        if (t == 0){
            float mx = -1e30f;
            for (int k=0;k<LBL;k++) mx = fmaxf(mx, lg[k]);
            float sm = 0.0f;
            for (int k=0;k<LBL;k++) sm += __expf(lg[k]-mx);
            sc[0] = mx; sc[1] = 1.0f / sm;
        }
        __syncthreads();
        if (t < LBL) out0[(size_t)row*LBL + t] = __expf(lg[t]-sc[0]) * sc[1];
    } else {
        // ----- loc geo path -----
        float* xr = (float*)smem;
        float* lg = xr + 512;
        const int row = bx - 576, t = tid;
        xr[t]       = X2[(size_t)row*512 + t];
        xr[t + 256] = X2[(size_t)row*512 + t + 256];
        __syncthreads();
        const int c = t >> 5, s = t & 31;
        float acc = 0.0f;
        if (c < 6){
            for (int k = s*16; k < (s+1)*16; k++) acc += xr[k] * loc_w2[(size_t)k*6 + c];
        }
        #pragma unroll
        for (int off=1; off<32; off<<=1) acc += __shfl_down(acc, off);
        if (s == 0 && c < 6) lg[c] = acc + loc_b2[c];
        __syncthreads();
        if (t == 0){
            const float o0=lg[0], o1=lg[1], f0=lg[2], f1=lg[3], f2=lg[4], f3=lg[5];
            geo[(size_t)row*5+0] = qlocs[(size_t)row*2+0] + o0;
            geo[(size_t)row*5+1] = qlocs[(size_t)row*2+1] + o1;
            geo[(size_t)row*5+2] = f0*f0 + f1*f1;
            geo[(size_t)row*5+3] = f0*f2 + f1*f3;
            geo[(size_t)row*5+4] = f2*f2 + f3*f3;
        }
    }
}

// ---------------- pair softmax v2: row-wise, separable quad, no flat decode ----------------
// grid 512 (one block per (b,q)), 1024 threads = 4 row-groups x 256 j-lanes
__global__ __launch_bounds__(1024) void pair_fused(
    const float* __restrict__ score, const float* __restrict__ geo,
    float* __restrict__ out1)
{
    const int bq = blockIdx.x, b = bq >> 7, t = threadIdx.x;
    __shared__ float s0[256], s1[256];
    __shared__ float red[16];
    __shared__ float bc;

    const float* sc0 = score + ((size_t)(b*2)*Qn + (bq & 127))*Ln;
    if (t < 256)      s0[t]       = sc0[t];
    else if (t < 512) s1[t - 256] = sc0[(size_t)Qn*Ln + (t - 256)];
    __syncthreads();

    // true m = max_i (s0[i] + max_{j>=i} s1[j]); computed redundantly per-wave (no barriers)
    const int lane = t & 63;
    const float4 s1v = *(const float4*)&s1[lane*4];
    const float4 s0v = *(const float4*)&s0[lane*4];
    float sfx = fmaxf(fmaxf(s1v.x, s1v.y), fmaxf(s1v.z, s1v.w));
    #pragma unroll
    for (int off = 1; off < 64; off <<= 1) {
        const int src = (lane + off < 64) ? (lane + off) : 63;
        const float v = __shfl(sfx, src, 64);
        if (lane + off < 64) sfx = fmaxf(sfx, v);
    }
    // sfx = max s1[4*lane .. 255]
    float nxt = __shfl(sfx, (lane < 63) ? (lane + 1) : 63, 64);
    if (lane == 63) nxt = -3.0e38f;
    float run = fmaxf(nxt, s1v.w);
    float cand = s0v.w + run;
    run = fmaxf(run, s1v.z); cand = fmaxf(cand, s0v.z + run);
    run = fmaxf(run, s1v.y); cand = fmaxf(cand, s0v.y + run);
    run = fmaxf(run, s1v.x); cand = fmaxf(cand, s0v.x + run);
    #pragma unroll
    for (int off = 1; off < 64; off <<= 1) cand = fmaxf(cand, __shfl_xor(cand, off, 64));
    const float m = cand;

    const float c0  = geo[(size_t)bq*5+0], c1  = geo[(size_t)bq*5+1];
    const float F00 = geo[(size_t)bq*5+2], F01 = geo[(size_t)bq*5+3], F11 = geo[(size_t)bq*5+4];
    const float F01x2 = 2.0f * F01;

    const int j = t & 255, g = t >> 8;
    const float d1 = (float)j - c1;
    const float Pj = s1[j] - F11 * d1 * d1 - m;   // per-lane constant (m folded in)

    // pass 1: sum of e
    float lsum = 0.0f;
    for (int i = g; i < 256; i += 4) {
        const float d0 = (float)i - c0;
        const float R = s0[i] - F00 * d0 * d0;
        const float G = F01x2 * d0;
        if (j >= i) lsum += __expf(fmaf(-G, d1, Pj) + R);
    }
    #pragma unroll
    for (int off = 1; off < 64; off <<= 1) lsum += __shfl_xor(lsum, off, 64);
    if (lane == 0) red[t >> 6] = lsum;
    __syncthreads();
    if (t == 0) {
        float tot = 0.0f;
        #pragma unroll
        for (int k = 0; k < 16; k++) tot += red[k];
        bc = 1.0f / (tot + 1e-12f);
    }
    __syncthreads();
    const float inv = bc;

    // pass 2: normalized stores, row-contiguous
    float* op = out1 + (size_t)bq * POUT;
    for (int i = g; i < 256; i += 4) {
        const float d0 = (float)i - c0;
        const float R = s0[i] - F00 * d0 * d0;
        const float G = F01x2 * d0;
        const int base = (i * (513 - i)) >> 1;
        if (j >= i) op[base + j - i] = __expf(fmaf(-G, d1, Pj) + R) * inv;
    }
}

extern "C" void kernel_launch(void* const* d_in, const int* in_sizes, int n_in,
                              void* d_out, int out_size, void* d_ws, size_t ws_size,
                              hipStream_t stream)
{
    const float* hiddens = (const float*)d_in[0];
    const void*  masks   = d_in[1];
    const float* queries = (const float*)d_in[2];
    const float* qlocs   = (const float*)d_in[3];
    const float* qlogits = (const float*)d_in[4];
    const float* cls_w1  = (const float*)d_in[5];
    const float* cls_b1  = (const float*)d_in[6];
    const float* cls_w2  = (const float*)d_in[7];
    const float* cls_b2  = (const float*)d_in[8];
    const float* tq_w    = (const float*)d_in[9];
    const float* tq_b    = (const float*)d_in[10];
    const float* tc_w    = (const float*)d_in[11];
    const float* tc_b    = (const float*)d_in[12];
    const float* loc_w1  = (const float*)d_in[13];
    const float* loc_b1  = (const float*)d_in[14];
    const float* loc_w2  = (const float*)d_in[15];
    const float* loc_b2  = (const float*)d_in[16];

    char* ws = (char*)d_ws;
    f16*   qf16  = (f16*)  (ws);                     // 1 MB  (512x1024)
    f16*   hf16  = (f16*)  (ws + (1u<<20));          // 2 MB  (1024x1024)
    float* X1    = (float*)(ws + (3u<<20));          // 1 MB  (512x512)
    float* X2    = (float*)(ws + (4u<<20));          // 1 MB
    f16*   qh    = (f16*)  (ws + (5u<<20));          // 2 MB  (512x2048)
    float* score = (float*)(ws + (7u<<20));          // 1 MB  (B,2,Q,L)
    float* geo   = (float*)(ws + (8u<<20));          // 10 KB

    float* out0 = (float*)d_out;
    float* out1 = out0 + (size_t)Bn*Qn*LBL;

    // big transient scratch inside out1 (fully overwritten by pair_fused at the end)
    f16* Wq_t = (f16*)out1;                                   // 3072x1024 f16 = 6 MB
    f16* Wc_t = (f16*)((char*)out1 + 6291456);                // 2048x1024 f16 = 4 MB
    f16* chh  = (f16*)((char*)out1 + 6291456 + 4194304);      // 1024x2048 f16 = 4 MB

    prep<<<dim3(6656), 256, 0, stream>>>(queries, hiddens, cls_w1, loc_w1, tq_w, tc_w,
                                         qf16, hf16, Wq_t, Wc_t);
    gemm128<<<dim3(224), 256, 0, stream>>>(qf16, hf16, Wq_t, Wc_t,
                                           cls_b1, loc_b1, tq_b, tc_b,
                                           X1, X2, qh, chh);
    score_heads<<<dim3(1088), 256, 0, stream>>>(qh, chh, masks, score,
                                                X1, cls_w2, cls_b2, qlogits, out0,
                                                X2, loc_w2, loc_b2, qlocs, geo);
    pair_fused<<<dim3(Bn*Qn), 1024, 0, stream>>>(score, geo, out1);
}

// Round 7
// 78.745 us; speedup vs baseline: 2.6816x; 1.1204x over previous
//
#include <hip/hip_runtime.h>
#include <math.h>

typedef _Float16 f16;
typedef __attribute__((ext_vector_type(4))) _Float16 f16x4;
typedef __attribute__((ext_vector_type(8))) _Float16 f16x8;
typedef __attribute__((ext_vector_type(4))) float f32x4;

#define Bn 4
#define Ln 256
#define Qn 128
#define Hn 1024
#define LBL 33
#define POUT 32896   // 256*257/2

__device__ __forceinline__ float gelu_exact(float x){
    return 0.5f * x * (1.0f + erff(x * 0.70710678118654752f));
}

__device__ __forceinline__ bool mask_at(const void* m, int idx, unsigned u0){
    if (u0 == 0x01010101u) return ((const unsigned char*)m)[idx] != 0;
    if (u0 == 0x3f800000u) return ((const float*)m)[idx] != 0.0f;
    return ((const int*)m)[idx] != 0;
}

__device__ __forceinline__ void gload16(const void* g, void* l){
    __builtin_amdgcn_global_load_lds(
        (const __attribute__((address_space(1))) unsigned int*)g,
        (__attribute__((address_space(3))) unsigned int*)l, 16, 0, 0);
}

// ---------------- prep: input f32->f16 cvt + weight cvt/transpose ----------------
// blocks [0,512): queries cvt ; [512,1536): hiddens cvt ; [1536,4096): weight transpose
// transpose tiles: 64 k-rows x 32 n-cols -> dst[n][k] f16, 16B writes
__global__ __launch_bounds__(256) void prep(
    const float* __restrict__ q, const float* __restrict__ h,
    const float* __restrict__ cls_w1, const float* __restrict__ loc_w1,
    const float* __restrict__ tq_w,  const float* __restrict__ tc_w,
    f16* __restrict__ qf, f16* __restrict__ hf,
    f16* __restrict__ Wq_t, f16* __restrict__ Wc_t)
{
    const int bx = blockIdx.x, t = threadIdx.x;
    if (bx < 1536) {
        if (bx < 512) {
            const int gid = bx*256 + t;
            const float4 v = ((const float4*)q)[gid];
            f16x4 o; o[0]=(f16)v.x; o[1]=(f16)v.y; o[2]=(f16)v.z; o[3]=(f16)v.w;
            *(f16x4*)&qf[(size_t)gid*4] = o;
        } else {
            const int gid = (bx-512)*256 + t;
            const float4 v = ((const float4*)h)[gid];
            f16x4 o; o[0]=(f16)v.x; o[1]=(f16)v.y; o[2]=(f16)v.z; o[3]=(f16)v.w;
            *(f16x4*)&hf[(size_t)gid*4] = o;
        }
        return;
    }
    const int tile = bx - 1536;     // 0..2559
    const float* src; f16* dst; int id, lg;
    if      (tile < 256)  { id = tile;        src = cls_w1; dst = Wq_t;                     lg = 4; }
    else if (tile < 512)  { id = tile - 256;  src = loc_w1; dst = Wq_t + (size_t)512*1024;  lg = 4; }
    else if (tile < 1536) { id = tile - 512;  src = tq_w;   dst = Wq_t + (size_t)1024*1024; lg = 6; }
    else                  { id = tile - 1536; src = tc_w;   dst = Wc_t;                     lg = 6; }
    const int N  = 32 << lg;
    const int n0 = (id & ((1<<lg)-1)) * 32;
    const int k0 = (id >> lg) * 64;

    __shared__ float X[64][33];
    const int rr = t >> 3, c4 = (t & 7) * 4;
    const float4 v0 = *(const float4*)&src[(size_t)(k0 + rr)      * N + n0 + c4];
    const float4 v1 = *(const float4*)&src[(size_t)(k0 + rr + 32) * N + n0 + c4];
    X[rr   ][c4+0] = v0.x; X[rr   ][c4+1] = v0.y; X[rr   ][c4+2] = v0.z; X[rr   ][c4+3] = v0.w;
    X[rr+32][c4+0] = v1.x; X[rr+32][c4+1] = v1.y; X[rr+32][c4+2] = v1.z; X[rr+32][c4+3] = v1.w;
    __syncthreads();
    const int n = t >> 3, kc = (t & 7) * 8;
    f16x8 o;
    #pragma unroll
    for (int u = 0; u < 8; u++) o[u] = (f16)X[kc + u][n];
    *(f16x8*)&dst[(size_t)(n0 + n) * 1024 + k0 + kc] = o;
}

// ---------------- fused 128x128-tile GEMM (m97 structure), K=1024 ----------------
__global__ __launch_bounds__(256) void gemm128(
    const f16* __restrict__ Aq, const f16* __restrict__ Ac,
    const f16* __restrict__ Wq, const f16* __restrict__ Wc,
    const float* __restrict__ cb1, const float* __restrict__ lb1,
    const float* __restrict__ tqb, const float* __restrict__ tcb,
    float* __restrict__ X1, float* __restrict__ X2,
    f16* __restrict__ qh, f16* __restrict__ chh)
{
    __shared__ __align__(16) f16 Ah[128*64];
    __shared__ __align__(16) f16 Bh[128*64];
    const int tid = threadIdx.x;
    const int w = tid >> 6, lane = tid & 63;
    const int wr = w >> 1, wcc = w & 1;
    const int lr = lane & 15, hi = lane >> 4;

    const int bx = blockIdx.x;
    const f16 *A, *Bt;
    int bm, bn, qside;
    if (bx < 96) { qside = 1; bm = bx / 24; bn = bx % 24; A = Aq; Bt = Wq; }
    else         { qside = 0; const int ix = bx - 96; bm = ix >> 4; bn = ix & 15; A = Ac; Bt = Wc; }

    const int lr8   = lane >> 3;
    const int lslot = (lane & 7) ^ lr8;
    const f16* Ag = A  + (size_t)(bm*128 + w*32) * 1024;
    const f16* Bg = Bt + (size_t)(bn*128 + w*32) * 1024;
    f16* AhW = &Ah[(w*32)*64];
    f16* BhW = &Bh[(w*32)*64];

    f32x4 acc[4][4] = {};

    for (int k0 = 0; k0 < 1024; k0 += 64) {
        #pragma unroll
        for (int i = 0; i < 4; i++) {
            gload16(Ag + (size_t)(i*8 + lr8)*1024 + k0 + lslot*8, AhW + i*8*64);
            gload16(Bg + (size_t)(i*8 + lr8)*1024 + k0 + lslot*8, BhW + i*8*64);
        }
        __syncthreads();
        #pragma unroll
        for (int ks = 0; ks < 2; ks++) {
            f16x8 a[4], b[4];
            #pragma unroll
            for (int mf = 0; mf < 4; mf++) {
                const int row = wr*64 + mf*16 + lr;
                const int sl  = (ks*4 + hi) ^ (lr & 7);
                a[mf] = *(const f16x8*)&Ah[row*64 + sl*8];
            }
            #pragma unroll
            for (int nf = 0; nf < 4; nf++) {
                const int row = wcc*64 + nf*16 + lr;
                const int sl  = (ks*4 + hi) ^ (lr & 7);
                b[nf] = *(const f16x8*)&Bh[row*64 + sl*8];
            }
            #pragma unroll
            for (int mf = 0; mf < 4; mf++)
                #pragma unroll
                for (int nf = 0; nf < 4; nf++)
                    acc[mf][nf] = __builtin_amdgcn_mfma_f32_16x16x32_f16(a[mf], b[nf], acc[mf][nf], 0, 0, 0);
        }
        __syncthreads();
    }

    const int r0 = hi * 4;
    #pragma unroll
    for (int nf = 0; nf < 4; nf++) {
        const int colg = bn*128 + wcc*64 + nf*16 + lr;
        if (qside) {
            if (bn < 4) {
                const float bv = cb1[colg];
                #pragma unroll
                for (int mf = 0; mf < 4; mf++)
                    #pragma unroll
                    for (int r = 0; r < 4; r++) {
                        const int row = bm*128 + wr*64 + mf*16 + r0 + r;
                        X1[(size_t)row*512 + colg] = gelu_exact(acc[mf][nf][r] + bv);
                    }
            } else if (bn < 8) {
                const int c2 = colg - 512;
                const float bv = lb1[c2];
                #pragma unroll
                for (int mf = 0; mf < 4; mf++)
                    #pragma unroll
                    for (int r = 0; r < 4; r++) {
                        const int row = bm*128 + wr*64 + mf*16 + r0 + r;
                        X2[(size_t)row*512 + c2] = gelu_exact(acc[mf][nf][r] + bv);
                    }
            } else {
                const int c2 = colg - 1024;
                const float bv = tqb[c2];
                #pragma unroll
                for (int mf = 0; mf < 4; mf++)
                    #pragma unroll
                    for (int r = 0; r < 4; r++) {
                        const int row = bm*128 + wr*64 + mf*16 + r0 + r;
                        qh[(size_t)row*2048 + c2] = (f16)(acc[mf][nf][r] + bv);
                    }
            }
        } else {
            const float bv = tcb[colg];
            #pragma unroll
            for (int mf = 0; mf < 4; mf++)
                #pragma unroll
                for (int r = 0; r < 4; r++) {
                    const int row = bm*128 + wr*64 + mf*16 + r0 + r;
                    chh[(size_t)row*2048 + colg] = (f16)(acc[mf][nf][r] + bv);
                }
        }
    }
}

// ---------------- fused: blocks [0,64) score einsum ; [64,576) cls softmax ; [576,1088) loc geo ----------------
__global__ __launch_bounds__(256) void score_heads(
    const f16* __restrict__ qh, const f16* __restrict__ chh,
    const void* __restrict__ maskp, float* __restrict__ score,
    const float* __restrict__ X1, const float* __restrict__ cls_w2,
    const float* __restrict__ cls_b2, const float* __restrict__ qlog, float* __restrict__ out0,
    const float* __restrict__ X2, const float* __restrict__ loc_w2,
    const float* __restrict__ loc_b2, const float* __restrict__ qlocs, float* __restrict__ geo)
{
    __shared__ __align__(16) char smem[64*72*2*2 + 64];
    const int bx = blockIdx.x, tid = threadIdx.x;

    if (bx < 64) {
        // ----- score path -----
        f16* Ah = (f16*)smem;             // [64][72]
        f16* Bh = Ah + 64*72;
        const int bc = bx & 7, b = bc >> 1, c = bc & 1;
        const int n0 = ((bx >> 3) & 3) * 64;
        const int m0 = (bx >> 5) * 64;
        const f16* Aq = qh  + (size_t)b*Qn*2048 + c*1024;
        const f16* Bv = chh + (size_t)b*Ln*2048 + c*1024;

        const int w = tid >> 6, lane = tid & 63;
        const int wr = w >> 1, wc = w & 1;
        const int lr = lane & 15, lk = (lane >> 4) * 8;
        const int rr = tid >> 3, gg = (tid & 7) * 8;

        f32x4 acc[2][2] = {};

        for (int k0 = 0; k0 < 1024; k0 += 64) {
            *(f16x8*)&Ah[(rr   )*72 + gg] = *(const f16x8*)(Aq + (size_t)(m0+rr   )*2048 + k0 + gg);
            *(f16x8*)&Ah[(rr+32)*72 + gg] = *(const f16x8*)(Aq + (size_t)(m0+rr+32)*2048 + k0 + gg);
            *(f16x8*)&Bh[(rr   )*72 + gg] = *(const f16x8*)(Bv + (size_t)(n0+rr   )*2048 + k0 + gg);
            *(f16x8*)&Bh[(rr+32)*72 + gg] = *(const f16x8*)(Bv + (size_t)(n0+rr+32)*2048 + k0 + gg);
            __syncthreads();
            #pragma unroll
            for (int ks=0; ks<64; ks+=32){
                f16x8 a[2], b2[2];
                #pragma unroll
                for (int mf=0; mf<2; mf++) a[mf]  = *(f16x8*)&Ah[(wr*32+mf*16+lr)*72 + ks+lk];
                #pragma unroll
                for (int nf=0; nf<2; nf++) b2[nf] = *(f16x8*)&Bh[(wc*32+nf*16+lr)*72 + ks+lk];
                #pragma unroll
                for (int mf=0; mf<2; mf++)
                    #pragma unroll
                    for (int nf=0; nf<2; nf++)
                        acc[mf][nf] = __builtin_amdgcn_mfma_f32_16x16x32_f16(a[mf], b2[nf], acc[mf][nf], 0, 0, 0);
            }
            __syncthreads();
        }

        const unsigned u0 = *(const unsigned*)maskp;
        const int r0 = (lane >> 4) * 4;
        #pragma unroll
        for (int nf=0; nf<2; nf++){
            const int v = n0 + wc*32 + nf*16 + lr;
            const bool mv = mask_at(maskp, b*Ln + v, u0);
            #pragma unroll
            for (int mf=0; mf<2; mf++){
                #pragma unroll
                for (int r=0; r<4; r++){
                    const int q = m0 + wr*32 + mf*16 + r0 + r;
                    float val = mv ? (acc[mf][nf][r] * 0.03125f) : -100000000.0f;
                    score[((size_t)(b*2+c)*Qn + q)*Ln + v] = val;
                }
            }
        }
    } else if (bx < 576) {
        // ----- cls softmax path -----
        float* xr = (float*)smem;         // 512
        float* lg = xr + 512;             // 64
        float* sc = lg + 64;              // 2
        const int row = bx - 64, t = tid;
        xr[t]       = X1[(size_t)row*512 + t];
        xr[t + 256] = X1[(size_t)row*512 + t + 256];
        __syncthreads();
        const int c = t >> 2, s = t & 3;
        float acc = 0.0f;
        if (c < LBL){
            for (int k = s*128; k < (s+1)*128; k++) acc += xr[k] * cls_w2[(size_t)k*LBL + c];
        }
        acc += __shfl_down(acc, 1);
        acc += __shfl_down(acc, 2);
        if (s == 0 && c < LBL) lg[c] = acc + cls_b2[c] + qlog[(size_t)row*LBL + c];
        __syncthreads();
        if (t == 0){
            float mx = -1e30f;
            for (int k=0;k<LBL;k++) mx = fmaxf(mx, lg[k]);
            float sm = 0.0f;
            for (int k=0;k<LBL;k++) sm += __expf(lg[k]-mx);
            sc[0] = mx; sc[1] = 1.0f / sm;
        }
        __syncthreads();
        if (t < LBL) out0[(size_t)row*LBL + t] = __expf(lg[t]-sc[0]) * sc[1];
    } else {
        // ----- loc geo path -----
        float* xr = (float*)smem;
        float* lg = xr + 512;
        const int row = bx - 576, t = tid;
        xr[t]       = X2[(size_t)row*512 + t];
        xr[t + 256] = X2[(size_t)row*512 + t + 256];
        __syncthreads();
        const int c = t >> 5, s = t & 31;
        float acc = 0.0f;
        if (c < 6){
            for (int k = s*16; k < (s+1)*16; k++) acc += xr[k] * loc_w2[(size_t)k*6 + c];
        }
        #pragma unroll
        for (int off=1; off<32; off<<=1) acc += __shfl_down(acc, off);
        if (s == 0 && c < 6) lg[c] = acc + loc_b2[c];
        __syncthreads();
        if (t == 0){
            const float o0=lg[0], o1=lg[1], f0=lg[2], f1=lg[3], f2=lg[4], f3=lg[5];
            geo[(size_t)row*5+0] = qlocs[(size_t)row*2+0] + o0;
            geo[(size_t)row*5+1] = qlocs[(size_t)row*2+1] + o1;
            geo[(size_t)row*5+2] = f0*f0 + f1*f1;
            geo[(size_t)row*5+3] = f0*f2 + f1*f3;
            geo[(size_t)row*5+4] = f2*f2 + f3*f3;
        }
    }
}

// ---------------- pair softmax v4: row-pair compaction, single pass, f32 register e ----------------
// Rows rp (0..127) and 255-rp share 256 lanes; the leftover element per pair
// (row 255-rp, j=255) is handled by threads t<128.
// val(i,j) = RG[i].x + RG[i].y * j + T[j]:
//   RG[i].x = s0[i] - F00*d0^2 - m + 2*F01*d0*c1 ; RG[i].y = -2*F01*d0 ; T[j] = s1[j] - F11*d1^2
// m = max(s0[i]+s1[j]) kept (reference epsilon semantics); e stays f32 (f16 underflows
// when all vals <= -10: f16 subnormal floor 6e-8 vs f32 1e-38 -- the round-5 bug).
__global__ __launch_bounds__(1024) void pair_fused(
    const float* __restrict__ score, const float* __restrict__ geo,
    float* __restrict__ out1)
{
    const int bq = blockIdx.x, b = bq >> 7, t = threadIdx.x;
    __shared__ float s0[256], s1[256];
    __shared__ float2 RG[256];
    __shared__ float T[256];
    __shared__ float red[16];
    __shared__ float bcv;

    const float* sc0 = score + ((size_t)(b*2)*Qn + (bq & 127))*Ln;
    if (t < 256)      s0[t]       = sc0[t];
    else if (t < 512) s1[t - 256] = sc0[(size_t)Qn*Ln + (t - 256)];
    __syncthreads();

    // true m = max_i (s0[i] + max_{j>=i} s1[j]); per-wave redundant (proven code)
    const int lane = t & 63;
    const float4 s1v = *(const float4*)&s1[lane*4];
    const float4 s0v = *(const float4*)&s0[lane*4];
    float sfx = fmaxf(fmaxf(s1v.x, s1v.y), fmaxf(s1v.z, s1v.w));
    #pragma unroll
    for (int off = 1; off < 64; off <<= 1) {
        const int src = (lane + off < 64) ? (lane + off) : 63;
        const float v = __shfl(sfx, src, 64);
        if (lane + off < 64) sfx = fmaxf(sfx, v);
    }
    float nxt = __shfl(sfx, (lane < 63) ? (lane + 1) : 63, 64);
    if (lane == 63) nxt = -3.0e38f;
    float run = fmaxf(nxt, s1v.w);
    float cand = s0v.w + run;
    run = fmaxf(run, s1v.z); cand = fmaxf(cand, s0v.z + run);
    run = fmaxf(run, s1v.y); cand = fmaxf(cand, s0v.y + run);
    run = fmaxf(run, s1v.x); cand = fmaxf(cand, s0v.x + run);
    #pragma unroll
    for (int off = 1; off < 64; off <<= 1) cand = fmaxf(cand, __shfl_xor(cand, off, 64));
    const float m = cand;

    const float c0  = geo[(size_t)bq*5+0], c1  = geo[(size_t)bq*5+1];
    const float F00 = geo[(size_t)bq*5+2], F01 = geo[(size_t)bq*5+3], F11 = geo[(size_t)bq*5+4];

    // precompute tables
    if (t < 256) {
        const float d0 = (float)t - c0;
        const float nG = -2.0f * F01 * d0;
        const float Rv = s0[t] - F00 * d0 * d0 - m;
        RG[t] = make_float2(Rv - nG * c1, nG);
        const float d1 = (float)t - c1;
        T[t] = s1[t] - F11 * d1 * d1;
    }
    __syncthreads();

    const int g = t >> 8, l = t & 255;
    const int rp0 = g * 32;

    float lsum = 0.0f;
    float ev[32];
    float ex = 0.0f;

    #pragma unroll
    for (int k = 0; k < 32; k++) {
        const int rp = rp0 + k;
        const bool r2 = (l + rp > 255);
        const int i = r2 ? (255 - rp) : rp;
        const int j = r2 ? (l - 1) : (rp + l);
        const float2 rg = RG[i];
        const float e = __expf(fmaf(rg.y, (float)j, rg.x) + T[j]);
        lsum += e;
        ev[k] = e;
    }
    if (t < 128) {
        const int i = 128 + t;
        const float2 rg = RG[i];
        ex = __expf(fmaf(rg.y, 255.0f, rg.x) + T[255]);
        lsum += ex;
    }

    // block sum -> inv
    #pragma unroll
    for (int off = 1; off < 64; off <<= 1) lsum += __shfl_xor(lsum, off, 64);
    if (lane == 0) red[t >> 6] = lsum;
    __syncthreads();
    if (t == 0) {
        float tot = 0.0f;
        #pragma unroll
        for (int k = 0; k < 16; k++) tot += red[k];
        bcv = 1.0f / (tot + 1e-12f);
    }
    __syncthreads();
    const float inv = bcv;

    // stores: row1 at tri(rp)+l ; row2 at tri(i2)+l+rp-256 ; epilogue row i, j=255
    float* op = out1 + (size_t)bq * POUT;
    #pragma unroll
    for (int k = 0; k < 32; k++) {
        const int rp = rp0 + k;
        const bool r2 = (l + rp > 255);
        const int i2 = 255 - rp;
        const int tri1 = (rp * (513 - rp)) >> 1;
        const int tri2 = ((i2 * (513 - i2)) >> 1) - (256 - rp);
        op[(r2 ? tri2 : tri1) + l] = ev[k] * inv;
    }
    if (t < 128) {
        const int i = 128 + t;
        op[((i * (513 - i)) >> 1) + 127 - t] = ex * inv;
    }
}

extern "C" void kernel_launch(void* const* d_in, const int* in_sizes, int n_in,
                              void* d_out, int out_size, void* d_ws, size_t ws_size,
                              hipStream_t stream)
{
    const float* hiddens = (const float*)d_in[0];
    const void*  masks   = d_in[1];
    const float* queries = (const float*)d_in[2];
    const float* qlocs   = (const float*)d_in[3];
    const float* qlogits = (const float*)d_in[4];
    const float* cls_w1  = (const float*)d_in[5];
    const float* cls_b1  = (const float*)d_in[6];
    const float* cls_w2  = (const float*)d_in[7];
    const float* cls_b2  = (const float*)d_in[8];
    const float* tq_w    = (const float*)d_in[9];
    const float* tq_b    = (const float*)d_in[10];
    const float* tc_w    = (const float*)d_in[11];
    const float* tc_b    = (const float*)d_in[12];
    const float* loc_w1  = (const float*)d_in[13];
    const float* loc_b1  = (const float*)d_in[14];
    const float* loc_w2  = (const float*)d_in[15];
    const float* loc_b2  = (const float*)d_in[16];

    char* ws = (char*)d_ws;
    f16*   qf16  = (f16*)  (ws);                     // 1 MB  (512x1024)
    f16*   hf16  = (f16*)  (ws + (1u<<20));          // 2 MB  (1024x1024)
    float* X1    = (float*)(ws + (3u<<20));          // 1 MB  (512x512)
    float* X2    = (float*)(ws + (4u<<20));          // 1 MB
    f16*   qh    = (f16*)  (ws + (5u<<20));          // 2 MB  (512x2048)
    float* score = (float*)(ws + (7u<<20));          // 1 MB  (B,2,Q,L)
    float* geo   = (float*)(ws + (8u<<20));          // 10 KB

    float* out0 = (float*)d_out;
    float* out1 = out0 + (size_t)Bn*Qn*LBL;

    // big transient scratch inside out1 (fully overwritten by pair_fused at the end)
    f16* Wq_t = (f16*)out1;                                   // 3072x1024 f16 = 6 MB
    f16* Wc_t = (f16*)((char*)out1 + 6291456);                // 2048x1024 f16 = 4 MB
    f16* chh  = (f16*)((char*)out1 + 6291456 + 4194304);      // 1024x2048 f16 = 4 MB

    prep<<<dim3(4096), 256, 0, stream>>>(queries, hiddens, cls_w1, loc_w1, tq_w, tc_w,
                                         qf16, hf16, Wq_t, Wc_t);
    gemm128<<<dim3(224), 256, 0, stream>>>(qf16, hf16, Wq_t, Wc_t,
                                           cls_b1, loc_b1, tq_b, tc_b,
                                           X1, X2, qh, chh);
    score_heads<<<dim3(1088), 256, 0, stream>>>(qh, chh, masks, score,
                                                X1, cls_w2, cls_b2, qlogits, out0,
                                                X2, loc_w2, loc_b2, qlocs, geo);
    pair_fused<<<dim3(Bn*Qn), 1024, 0, stream>>>(score, geo, out1);
}